// Round 13
// baseline (777.217 us; speedup 1.0000x reference)
//
#include <hip/hip_runtime.h>

#define LL 12
#define NN 2048
#define KK 8
#define SS 4
#define HH 256
#define LN (LL*NN)
#define VV 50000
#define ZROW 4096
#define SROW 2048   // bytes per packed state row: [c f32 256 | h bf16 256 | Hf bf16 256]

typedef __bf16 bf16_t;
typedef __bf16 bf16x8 __attribute__((ext_vector_type(8)));
typedef __bf16 bf16x4v __attribute__((ext_vector_type(4)));
typedef float f32x4 __attribute__((ext_vector_type(4)));

__device__ __forceinline__ float sigmoidf_(float x) { return 1.f / (1.f + expf(-x)); }

// ---------------- E f32 -> bf16 (fallback path only) ----------------
__global__ __launch_bounds__(256) void k_cvtE(const float* __restrict__ src,
                                              bf16_t* __restrict__ dst, int n4)
{
    int i = blockIdx.x * 256 + threadIdx.x;
    const int stride = gridDim.x * 256;
    for (; i < n4; i += stride) {
        const float4 v = ((const float4*)src)[i];
        bf16x4v o;
        o[0] = (bf16_t)v.x; o[1] = (bf16_t)v.y; o[2] = (bf16_t)v.z; o[3] = (bf16_t)v.w;
        ((bf16x4v*)dst)[i] = o;
    }
}

// ---------------- weight transposes (f32 (K,N) -> bf16 (N,K)) ----------------
__global__ __launch_bounds__(256) void k_cvtW(
    const float* __restrict__ linW, const float* __restrict__ WW,
    const float* __restrict__ UfW, const float* __restrict__ UiW,
    bf16_t* __restrict__ linWt, bf16_t* __restrict__ WWt,
    bf16_t* __restrict__ UfWt, bf16_t* __restrict__ UiWt)
{
    int i = blockIdx.x * 256 + threadIdx.x;      // total 786432
    if (i < 262144) {                            // linW (1024,256) -> (256,1024)
        const int rr = i >> 8, cc = i & 255;
        linWt[(size_t)cc * 1024 + rr] = (bf16_t)linW[i];
        return;
    }
    i -= 262144;
    if (i < 262144) {                            // WW (256,1024) -> (1024,256)
        const int rr = i >> 10, cc = i & 1023;
        WWt[(size_t)cc * 256 + rr] = (bf16_t)WW[i];
        return;
    }
    i -= 262144;
    if (i < 65536) {                             // UfW (256,256) -> (256,256)
        const int rr = i >> 8, cc = i & 255;
        UfWt[(size_t)cc * 256 + rr] = (bf16_t)UfW[i];
        return;
    }
    i -= 65536;
    if (i < 196608) {                            // UiW (256,768) -> (768,256)
        const int rr = i / 768, cc = i - rr * 768;
        UiWt[(size_t)cc * 256 + rr] = (bf16_t)UiW[i];
    }
}

// ---------------- zero the dummy rows of both packed state buffers ----------------
__global__ __launch_bounds__(256) void k_zero(float* __restrict__ SA, float* __restrict__ SB)
{
    const int t = threadIdx.x;
    float* a = SA + (size_t)ZROW * 512;   // 512 f32 per 2KB row
    float* b = SB + (size_t)ZROW * 512;
    a[t] = 0.f; a[t + 256] = 0.f;
    b[t] = 0.f; b[t + 256] = 0.f;
}

// ---------------- G-table GEMM: G_s = E @ L_s (+ lin_b for s==0), coalesced A ----------------
// grid (4, 782) x 256 thr (2x2 waves); block tile 64 rows x 256 cols, K=256.
__global__ __launch_bounds__(256) void k_G(
    const float* __restrict__ E, const bf16_t* __restrict__ linWt,
    const float* __restrict__ linb, bf16_t* __restrict__ G)
{
    const int s = blockIdx.x;
    const int m0 = blockIdx.y * 64;
    const int t = threadIdx.x;
    const int lane = t & 63, w = t >> 6;
    const int wm = w >> 1, wn = w & 1;
    const int r = lane & 15, kg = lane >> 4;
    const int row0 = m0 + wm * 32 + r, row1 = row0 + 16;
    const float* a0p = E + (size_t)(row0 < VV ? row0 : 0) * HH + kg * 8;
    const float* a1p = E + (size_t)(row1 < VV ? row1 : 0) * HH + kg * 8;
    const bf16_t* bp[8];
    #pragma unroll
    for (int j = 0; j < 8; ++j)
        bp[j] = linWt + (size_t)(wn * 128 + j * 16 + r) * 1024 + s * 256 + kg * 8;

    const f32x4 zero = {0.f, 0.f, 0.f, 0.f};
    f32x4 acc[2][8];
    #pragma unroll
    for (int mi = 0; mi < 2; ++mi)
        #pragma unroll
        for (int j = 0; j < 8; ++j) acc[mi][j] = zero;

    for (int k0 = 0; k0 < 256; k0 += 32) {
        const float4 u0 = *(const float4*)(a0p + k0);
        const float4 u1 = *(const float4*)(a0p + k0 + 4);
        const float4 v0 = *(const float4*)(a1p + k0);
        const float4 v1 = *(const float4*)(a1p + k0 + 4);
        bf16x8 a0, a1;
        a0[0] = (bf16_t)u0.x; a0[1] = (bf16_t)u0.y; a0[2] = (bf16_t)u0.z; a0[3] = (bf16_t)u0.w;
        a0[4] = (bf16_t)u1.x; a0[5] = (bf16_t)u1.y; a0[6] = (bf16_t)u1.z; a0[7] = (bf16_t)u1.w;
        a1[0] = (bf16_t)v0.x; a1[1] = (bf16_t)v0.y; a1[2] = (bf16_t)v0.z; a1[3] = (bf16_t)v0.w;
        a1[4] = (bf16_t)v1.x; a1[5] = (bf16_t)v1.y; a1[6] = (bf16_t)v1.z; a1[7] = (bf16_t)v1.w;
        #pragma unroll
        for (int j = 0; j < 8; ++j) {
            const bf16x8 b = *(const bf16x8*)bp[j];
            acc[0][j] = __builtin_amdgcn_mfma_f32_16x16x32_bf16(a0, b, acc[0][j], 0, 0, 0);
            acc[1][j] = __builtin_amdgcn_mfma_f32_16x16x32_bf16(a1, b, acc[1][j], 0, 0, 0);
            bp[j] += 32;
        }
    }
    const int crow = m0 + wm * 32 + kg * 4;
    bf16_t* Gs = G + (size_t)s * VV * HH;
    #pragma unroll
    for (int j = 0; j < 8; ++j) {
        const int ccol = wn * 128 + j * 16 + r;
        const float bv = (s == 0) ? linb[ccol] : 0.f;
        #pragma unroll
        for (int mi = 0; mi < 2; ++mi)
            #pragma unroll
            for (int jj = 0; jj < 4; ++jj) {
                const int grow = crow + mi * 16 + jj;
                if (grow < VV)
                    Gs[(size_t)grow * HH + ccol] = (bf16_t)(acc[mi][j][jj] + bv);
            }
    }
}

// ---------------- embed v4: pure 4-way gather-sum from G tables ----------------
// 768 blocks x 256 thr; block = 64 rows; thread = (slice sl, row-group rb) x 8 rows.
__global__ __launch_bounds__(256) void k_embed2(
    const int* __restrict__ tok1, const int* __restrict__ tok2,
    const bf16_t* __restrict__ G, bf16_t* __restrict__ xbf)
{
    const int t = threadIdx.x;
    const int m0 = blockIdx.x * 64;
    const int sl = t & 31, rb = t >> 5;
    #pragma unroll
    for (int i = 0; i < 8; ++i) {
        const int m = m0 + rb + i * 8;
        const int e = (m >= LN) ? 1 : 0;
        const int rrow = m - e * LN;
        const int4 tk = *(const int4*)((e ? tok2 : tok1) + (size_t)rrow * SS);
        const bf16x8 g0 = *(const bf16x8*)(G + ((size_t)0 * VV + tk.x) * HH + sl * 8);
        const bf16x8 g1 = *(const bf16x8*)(G + ((size_t)1 * VV + tk.y) * HH + sl * 8);
        const bf16x8 g2 = *(const bf16x8*)(G + ((size_t)2 * VV + tk.z) * HH + sl * 8);
        const bf16x8 g3 = *(const bf16x8*)(G + ((size_t)3 * VV + tk.w) * HH + sl * 8);
        bf16x8 o;
        #pragma unroll
        for (int j = 0; j < 8; ++j)
            o[j] = (bf16_t)((float)g0[j] + (float)g1[j] + (float)g2[j] + (float)g3[j]);
        *(bf16x8*)(xbf + (size_t)m * HH + sl * 8) = o;
    }
}

// ---------------- embed GEMM (fallback, measured-best round-3): 768 blocks x 256 thr ----------------
__global__ __launch_bounds__(256) void k_embed(
    const int* __restrict__ tok1, const int* __restrict__ tok2,
    const bf16_t* __restrict__ Ebf, const bf16_t* __restrict__ linWt,
    const float* __restrict__ linb, bf16_t* __restrict__ xout)
{
    __shared__ int toff[64][SS];
    const int t = threadIdx.x;
    const int m0 = blockIdx.x * 64;
    {
        const int lr = t >> 2, s = t & 3;
        const int m = m0 + lr;
        const int e = (m >= LN) ? 1 : 0;
        const int rrow = m - e * LN;
        const int* tok = e ? tok2 : tok1;
        toff[lr][s] = tok[(size_t)rrow * SS + s] * HH;
    }
    __syncthreads();
    const int lane = t & 63, w = t >> 6;
    const int wm = w >> 1, wn = w & 1;
    const int r = lane & 15, kg = lane >> 4;
    const int lr0 = wm * 32 + r, lr1 = lr0 + 16;
    const bf16_t* bp[8];
    #pragma unroll
    for (int j = 0; j < 8; ++j)
        bp[j] = linWt + (size_t)(wn * 128 + j * 16 + r) * 1024 + kg * 8;

    const f32x4 zero = {0.f, 0.f, 0.f, 0.f};
    f32x4 acc[2][8];
    #pragma unroll
    for (int mi = 0; mi < 2; ++mi)
        #pragma unroll
        for (int j = 0; j < 8; ++j) acc[mi][j] = zero;

    for (int k0 = 0; k0 < 1024; k0 += 32) {
        const int s = k0 >> 8, off = (k0 & 255) + kg * 8;
        const bf16x8 a0 = *(const bf16x8*)(Ebf + (size_t)toff[lr0][s] + off);
        const bf16x8 a1 = *(const bf16x8*)(Ebf + (size_t)toff[lr1][s] + off);
        #pragma unroll
        for (int j = 0; j < 8; ++j) {
            const bf16x8 b = *(const bf16x8*)bp[j];
            acc[0][j] = __builtin_amdgcn_mfma_f32_16x16x32_bf16(a0, b, acc[0][j], 0, 0, 0);
            acc[1][j] = __builtin_amdgcn_mfma_f32_16x16x32_bf16(a1, b, acc[1][j], 0, 0, 0);
            bp[j] += 32;
        }
    }
    const int crow = m0 + wm * 32 + kg * 4;
    #pragma unroll
    for (int j = 0; j < 8; ++j) {
        const int ccol = wn * 128 + j * 16 + r;
        const float bv = linb[ccol];
        #pragma unroll
        for (int mi = 0; mi < 2; ++mi)
            #pragma unroll
            for (int jj = 0; jj < 4; ++jj)
                xout[(size_t)(crow + mi * 16 + jj) * HH + ccol] =
                    (bf16_t)(acc[mi][j][jj] + bv);
    }
}

// ---------------- fused step kernel (round-11): software-pipelined, register gates ----------------
__global__ __launch_bounds__(512, 2) void k_step(
    const bf16_t* __restrict__ xbf,
    const int* __restrict__ idx1, const int* __restrict__ idx2, const int l,
    const bf16_t* __restrict__ UfWt, const float* __restrict__ Ufb,
    const bf16_t* __restrict__ UiWt, const float* __restrict__ Uib,
    const bf16_t* __restrict__ WWt, const float* __restrict__ Wb,
    const char* __restrict__ Sprev, char* __restrict__ Snext)
{
    __shared__ __align__(16) bf16_t WxL[16 * 1024];   // 32 KB
    __shared__ __align__(16) bf16_t iuoL[16 * 768];   // 24 KB
    __shared__ __align__(16) bf16_t hsumL[16 * 256];  // 8 KB (hsum, later h_next; swizzled)

    const int t = threadIdx.x;
    const int bid = blockIdx.x;
    const int x  = bid & 7;
    const int e  = x >> 2;
    const int n0 = ((bid >> 3) * 4 + (x & 3)) * 16;
    const int g0 = e * NN + n0;
    const int lane = t & 63, w = t >> 6;
    const int r = lane & 15, kg = lane >> 4;
    const f32x4 zero = {0.f, 0.f, 0.f, 0.f};

    const int rr = t >> 5, sl = t & 31;
    const int ss = (sl + 4 * (rr & 7)) & 31;

    int ch[KK];
    {
        const int* idxp = (e ? idx2 : idx1) + ((size_t)l * NN + n0 + rr) * KK;
        const int4 i0 = *(const int4*)idxp;
        const int4 i1 = *(const int4*)(idxp + 4);
        ch[0] = i0.x; ch[1] = i0.y; ch[2] = i0.z; ch[3] = i0.w;
        ch[4] = i1.x; ch[5] = i1.y; ch[6] = i1.z; ch[7] = i1.w;
        #pragma unroll
        for (int k = 0; k < KK; ++k)
            ch[k] = (ch[k] >= 1) ? (e * NN + ch[k] - 1) : ZROW;
    }

    bf16x8 hv[KK];
    #pragma unroll
    for (int k = 0; k < KK; ++k)
        hv[k] = *(const bf16x8*)(Sprev + (size_t)ch[k] * SROW + 1024 + sl * 16);

    const bf16_t* xrow = xbf + ((size_t)e * LN + (size_t)l * NN + n0 + r) * HH + kg * 8;
    bf16x8 aWx[8];
    #pragma unroll
    for (int k = 0; k < 8; ++k) aWx[k] = *(const bf16x8*)(xrow + k * 32);

    {
        const bf16_t* bw[8];
        #pragma unroll
        for (int j = 0; j < 8; ++j)
            bw[j] = WWt + (size_t)((8 * w + j) * 16 + r) * HH + kg * 8;
        f32x4 acc[8];
        #pragma unroll
        for (int j = 0; j < 8; ++j) acc[j] = zero;
        #pragma unroll
        for (int k = 0; k < 8; ++k) {
            #pragma unroll
            for (int j = 0; j < 8; ++j) {
                const bf16x8 b = *(const bf16x8*)bw[j];
                acc[j] = __builtin_amdgcn_mfma_f32_16x16x32_bf16(aWx[k], b, acc[j], 0, 0, 0);
                bw[j] += 32;
            }
        }
        #pragma unroll
        for (int j = 0; j < 8; ++j) {
            const int col = (8 * w + j) * 16 + r;
            const float bv = Wb[col];
            #pragma unroll
            for (int jj = 0; jj < 4; ++jj)
                WxL[(size_t)(kg * 4 + jj) * 1024 + col] = (bf16_t)(acc[j][jj] + bv);
        }
    }

    {
        float hs[8] = {0.f, 0.f, 0.f, 0.f, 0.f, 0.f, 0.f, 0.f};
        #pragma unroll
        for (int k = 0; k < KK; ++k) {
            #pragma unroll
            for (int j = 0; j < 8; ++j) hs[j] += (float)hv[k][j];
        }
        bf16x8 o;
        #pragma unroll
        for (int j = 0; j < 8; ++j) o[j] = (bf16_t)hs[j];
        *(bf16x8*)(hsumL + rr * 256 + ss * 8) = o;
    }
    __syncthreads();   // SYNC1

    float4 cv0[KK], cv1[KK];
    bf16x8 fv[KK];
    #pragma unroll
    for (int k = 0; k < KK; ++k) {
        const char* row = Sprev + (size_t)ch[k] * SROW;
        cv0[k] = *(const float4*)(row + sl * 32);
        cv1[k] = *(const float4*)(row + sl * 32 + 16);
        fv[k]  = *(const bf16x8*)(row + 1536 + sl * 16);
    }

    {
        const bf16_t* bu[6];
        #pragma unroll
        for (int j = 0; j < 6; ++j)
            bu[j] = UiWt + (size_t)((6 * w + j) * 16 + r) * HH + kg * 8;
        f32x4 acc[6];
        #pragma unroll
        for (int j = 0; j < 6; ++j) acc[j] = zero;
        for (int k0 = 0; k0 < HH; k0 += 32) {
            const int sa = (((k0 >> 3) + kg) + 4 * (r & 7)) & 31;
            const bf16x8 a = *(const bf16x8*)(hsumL + r * 256 + sa * 8);
            #pragma unroll
            for (int j = 0; j < 6; ++j) {
                const bf16x8 b = *(const bf16x8*)bu[j];
                acc[j] = __builtin_amdgcn_mfma_f32_16x16x32_bf16(a, b, acc[j], 0, 0, 0);
                bu[j] += 32;
            }
        }
        #pragma unroll
        for (int j = 0; j < 6; ++j) {
            const int col = (6 * w + j) * 16 + r;
            const float bv = Uib[col];
            #pragma unroll
            for (int jj = 0; jj < 4; ++jj)
                iuoL[(size_t)(kg * 4 + jj) * 768 + col] = (bf16_t)(acc[j][jj] + bv);
        }
    }

    float ba[8] = {0.f, 0.f, 0.f, 0.f, 0.f, 0.f, 0.f, 0.f};
    {
        float wf[8];
        const bf16x8 wv = *(const bf16x8*)(WxL + (size_t)rr * 1024 + sl * 8);
        #pragma unroll
        for (int j = 0; j < 8; ++j) wf[j] = (float)wv[j];
        #pragma unroll
        for (int k = 0; k < KK; ++k) {
            const float cc[8] = {cv0[k].x, cv0[k].y, cv0[k].z, cv0[k].w,
                                 cv1[k].x, cv1[k].y, cv1[k].z, cv1[k].w};
            #pragma unroll
            for (int j = 0; j < 8; ++j) {
                const float fk = sigmoidf_(wf[j] + (float)fv[k][j]);
                ba[j] = fmaf(fk, cc[j], ba[j]);
            }
        }
    }
    __syncthreads();   // SYNC2

    {
        const bf16x8 wiv = *(const bf16x8*)(WxL + (size_t)rr * 1024 + 256 + sl * 8);
        const bf16x8 wuv = *(const bf16x8*)(WxL + (size_t)rr * 1024 + 512 + sl * 8);
        const bf16x8 wov = *(const bf16x8*)(WxL + (size_t)rr * 1024 + 768 + sl * 8);
        const bf16x8 iv  = *(const bf16x8*)(iuoL + (size_t)rr * 768 + sl * 8);
        const bf16x8 uv  = *(const bf16x8*)(iuoL + (size_t)rr * 768 + 256 + sl * 8);
        const bf16x8 ov  = *(const bf16x8*)(iuoL + (size_t)rr * 768 + 512 + sl * 8);
        float nc[8];
        bf16x8 nhb;
        #pragma unroll
        for (int j = 0; j < 8; ++j) {
            const float ig = sigmoidf_((float)iv[j] + (float)wiv[j]);
            const float ug = tanhf((float)uv[j] + (float)wuv[j]);
            const float og = sigmoidf_((float)ov[j] + (float)wov[j]);
            nc[j] = fmaf(ig, ug, ba[j]);
            nhb[j] = (bf16_t)(og * tanhf(nc[j]));
        }
        char* rowN = Snext + (size_t)(g0 + rr) * SROW;
        const f32x4 c0 = {nc[0], nc[1], nc[2], nc[3]};
        const f32x4 c1 = {nc[4], nc[5], nc[6], nc[7]};
        *(f32x4*)(rowN + sl * 32) = c0;
        *(f32x4*)(rowN + sl * 32 + 16) = c1;
        *(bf16x8*)(rowN + 1024 + sl * 16) = nhb;
        *(bf16x8*)(hsumL + rr * 256 + ss * 8) = nhb;
    }

    if (l < LL - 1) {
        __syncthreads();   // SYNC3
        const int ct0 = 2 * w;
        const bf16_t* bq0 = UfWt + (size_t)(ct0 * 16 + r) * HH + kg * 8;
        const bf16_t* bq1 = bq0 + (size_t)16 * HH;
        f32x4 ac0 = zero, ac1 = zero;
        for (int k0 = 0; k0 < HH; k0 += 32) {
            const int sa = (((k0 >> 3) + kg) + 4 * (r & 7)) & 31;
            const bf16x8 a = *(const bf16x8*)(hsumL + r * 256 + sa * 8);
            const bf16x8 b0 = *(const bf16x8*)bq0;
            const bf16x8 b1 = *(const bf16x8*)bq1;
            ac0 = __builtin_amdgcn_mfma_f32_16x16x32_bf16(a, b0, ac0, 0, 0, 0);
            ac1 = __builtin_amdgcn_mfma_f32_16x16x32_bf16(a, b1, ac1, 0, 0, 0);
            bq0 += 32; bq1 += 32;
        }
        const int c0 = ct0 * 16 + r, c1 = c0 + 16;
        const float bv0 = Ufb[c0], bv1 = Ufb[c1];
        #pragma unroll
        for (int jj = 0; jj < 4; ++jj) {
            bf16_t* fr = (bf16_t*)(Snext + (size_t)(g0 + kg * 4 + jj) * SROW + 1536);
            fr[c0] = (bf16_t)(ac0[jj] + bv0);
            fr[c1] = (bf16_t)(ac1[jj] + bv1);
        }
    }
}

// ---------------- siamese head (h read from packed state) ----------------
__global__ __launch_bounds__(256) void k_final(
    const char* __restrict__ Sfin, const bf16_t* __restrict__ xbf,
    const float* __restrict__ dW, const float* __restrict__ db,
    const float* __restrict__ oW, const float* __restrict__ ob,
    float* __restrict__ out)
{
    __shared__ __align__(16) float ad[8][HH];
    __shared__ __align__(16) float xx[8][512];
    const int t = threadIdx.x;
    const int n0 = blockIdx.x * 8;
    const size_t xoff1 = (size_t)(LL - 1) * NN * HH;
    const size_t xoff2 = (size_t)LN * HH + xoff1;
    #pragma unroll
    for (int rr = 0; rr < 8; ++rr) {
        const int n = n0 + rr;
        const float h1 = (float)((const bf16_t*)(Sfin + (size_t)n * SROW + 1024))[t]
                       + (float)xbf[xoff1 + (size_t)n * HH + t];
        const float h2 = (float)((const bf16_t*)(Sfin + (size_t)(NN + n) * SROW + 1024))[t]
                       + (float)xbf[xoff2 + (size_t)n * HH + t];
        ad[rr][t] = fabsf(h1 - h2);
    }
    __syncthreads();
    float a0[8], a1[8];
    #pragma unroll
    for (int rr = 0; rr < 8; ++rr) { a0[rr] = 0.f; a1[rr] = 0.f; }
    for (int k = 0; k < HH; k += 4) {
        #pragma unroll
        for (int kk = 0; kk < 4; ++kk) {
            const float b0 = dW[(size_t)(k + kk) * 512 + t];
            const float b1 = dW[(size_t)(k + kk) * 512 + 256 + t];
            #pragma unroll
            for (int rr = 0; rr < 8; ++rr) {
                const float av = ad[rr][k + kk];
                a0[rr] = fmaf(av, b0, a0[rr]);
                a1[rr] = fmaf(av, b1, a1[rr]);
            }
        }
    }
    const float db0 = db[t], db1 = db[256 + t];
    #pragma unroll
    for (int rr = 0; rr < 8; ++rr) {
        xx[rr][t] = tanhf(a0[rr] + db0);
        xx[rr][256 + t] = tanhf(a1[rr] + db1);
    }
    __syncthreads();
    const int w = t >> 6, lane = t & 63;
    for (int rr = w; rr < 8; rr += 4) {
        float p0 = 0.f, p1 = 0.f;
        for (int k = lane; k < 512; k += 64) {
            const float xv = xx[rr][k];
            p0 = fmaf(xv, oW[2 * k + 0], p0);
            p1 = fmaf(xv, oW[2 * k + 1], p1);
        }
        #pragma unroll
        for (int off = 32; off > 0; off >>= 1) {
            p0 += __shfl_down(p0, off);
            p1 += __shfl_down(p1, off);
        }
        if (lane == 0) {
            const float l0 = p0 + ob[0], l1 = p1 + ob[1];
            const float mx = fmaxf(l0, l1);
            const float e0 = expf(l0 - mx), e1 = expf(l1 - mx);
            const float inv = 1.f / (e0 + e1);
            out[(size_t)(n0 + rr) * 2 + 0] = e0 * inv;
            out[(size_t)(n0 + rr) * 2 + 1] = e1 * inv;
        }
    }
}

extern "C" void kernel_launch(void* const* d_in, const int* in_sizes, int n_in,
                              void* d_out, int out_size, void* d_ws, size_t ws_size,
                              hipStream_t stream) {
    (void)in_sizes; (void)n_in; (void)out_size;
    const int*   tok1 = (const int*)d_in[0];
    const int*   idx1 = (const int*)d_in[1];
    const int*   tok2 = (const int*)d_in[2];
    const int*   idx2 = (const int*)d_in[3];
    const float* E    = (const float*)d_in[4];
    const float* linW = (const float*)d_in[5];
    const float* linb = (const float*)d_in[6];
    const float* UfW  = (const float*)d_in[7];
    const float* Ufb  = (const float*)d_in[8];
    const float* UiW  = (const float*)d_in[9];
    const float* Uib  = (const float*)d_in[10];
    const float* WW   = (const float*)d_in[11];
    const float* Wb   = (const float*)d_in[12];
    const float* dW   = (const float*)d_in[13];
    const float* db   = (const float*)d_in[14];
    const float* oW   = (const float*)d_in[15];
    const float* ob   = (const float*)d_in[16];
    float* out = (float*)d_out;

    const size_t NEED_G = 25165824ull + 102400000ull + 1572864ull;  // 129,138,688 B
    bf16_t* xbf = (bf16_t*)d_ws;                        // 12,582,912 elems (25,165,824 B)
    char*   uni = (char*)(xbf + (size_t)12582912);

    if (ws_size >= NEED_G) {
        // ---- G-table path: xbf | G (SA/SB alias G) | weights ----
        bf16_t* G   = (bf16_t*)uni;                     // 102,400,000 B
        char*   SA  = uni;                              // aliases G (G dead after embed2)
        char*   SB  = uni + 8390656;
        char*   wts = uni + 102400000;
        bf16_t* linWt = (bf16_t*)wts;                   // 262,144 elems
        bf16_t* WWt   = linWt + (size_t)262144;
        bf16_t* UfWt  = WWt   + (size_t)262144;
        bf16_t* UiWt  = UfWt  + (size_t)65536;

        k_cvtW<<<3072, 256, 0, stream>>>(linW, WW, UfW, UiW, linWt, WWt, UfWt, UiWt);
        k_G<<<dim3(4, (VV + 63) / 64), 256, 0, stream>>>(E, linWt, linb, G);
        k_embed2<<<768, 256, 0, stream>>>(tok1, tok2, G, xbf);
        k_zero<<<1, 256, 0, stream>>>((float*)SA, (float*)SB);

        char *Sp = SA, *Sn = SB;
        for (int l = 0; l < LL; ++l) {
            k_step<<<256, 512, 0, stream>>>(xbf, idx1, idx2, l,
                                            UfWt, Ufb, UiWt, Uib, WWt, Wb, Sp, Sn);
            char* ts = Sp; Sp = Sn; Sn = ts;
        }
        k_final<<<NN / 8, 256, 0, stream>>>(Sp, xbf, dW, db, oW, ob, out);
    } else {
        // ---- fallback (round-11): xbf | UNION{ Ebf | SA SB } | weights ----
        bf16_t* Ebf = (bf16_t*)uni;                     // 25.6 MB
        char*   SA  = uni;
        char*   SB  = uni + 8390656;
        bf16_t* linWt = (bf16_t*)(uni + 25600000);
        bf16_t* WWt   = linWt + (size_t)262144;
        bf16_t* UfWt  = WWt   + (size_t)262144;
        bf16_t* UiWt  = UfWt  + (size_t)65536;

        k_cvtE<<<2048, 256, 0, stream>>>(E, Ebf, VV * HH / 4);
        k_cvtW<<<3072, 256, 0, stream>>>(linW, WW, UfW, UiW, linWt, WWt, UfWt, UiWt);
        k_embed<<<768, 256, 0, stream>>>(tok1, tok2, Ebf, linWt, linb, xbf);
        k_zero<<<1, 256, 0, stream>>>((float*)SA, (float*)SB);

        char *Sp = SA, *Sn = SB;
        for (int l = 0; l < LL; ++l) {
            k_step<<<256, 512, 0, stream>>>(xbf, idx1, idx2, l,
                                            UfWt, Ufb, UiWt, Uib, WWt, Wb, Sp, Sn);
            char* ts = Sp; Sp = Sn; Sn = ts;
        }
        k_final<<<NN / 8, 256, 0, stream>>>(Sp, xbf, dW, db, oW, ob, out);
    }
}

// Round 14
// 701.585 us; speedup vs baseline: 1.1078x; 1.1078x over previous
//
#include <hip/hip_runtime.h>

#define LL 12
#define NN 2048
#define KK 8
#define SS 4
#define HH 256
#define LN (LL*NN)
#define VV 50000
#define ZROW 4096
#define SROW 1536   // bytes per packed state row: [h bf16 256 | Hf bf16 256 | c bf16 256]

typedef __bf16 bf16_t;
typedef __bf16 bf16x8 __attribute__((ext_vector_type(8)));
typedef __bf16 bf16x4v __attribute__((ext_vector_type(4)));
typedef float f32x4 __attribute__((ext_vector_type(4)));

__device__ __forceinline__ float sigmoidf_(float x) { return 1.f / (1.f + expf(-x)); }

// ---------------- E f32 -> bf16 ----------------
__global__ __launch_bounds__(256) void k_cvtE(const float* __restrict__ src,
                                              bf16_t* __restrict__ dst, int n4)
{
    int i = blockIdx.x * 256 + threadIdx.x;
    const int stride = gridDim.x * 256;
    for (; i < n4; i += stride) {
        const float4 v = ((const float4*)src)[i];
        bf16x4v o;
        o[0] = (bf16_t)v.x; o[1] = (bf16_t)v.y; o[2] = (bf16_t)v.z; o[3] = (bf16_t)v.w;
        ((bf16x4v*)dst)[i] = o;
    }
}

// ---------------- weight transposes (f32 (K,N) -> bf16 (N,K)) ----------------
__global__ __launch_bounds__(256) void k_cvtW(
    const float* __restrict__ linW, const float* __restrict__ WW,
    const float* __restrict__ UfW, const float* __restrict__ UiW,
    bf16_t* __restrict__ linWt, bf16_t* __restrict__ WWt,
    bf16_t* __restrict__ UfWt, bf16_t* __restrict__ UiWt)
{
    int i = blockIdx.x * 256 + threadIdx.x;      // total 786432
    if (i < 262144) {                            // linW (1024,256) -> (256,1024)
        const int rr = i >> 8, cc = i & 255;
        linWt[(size_t)cc * 1024 + rr] = (bf16_t)linW[i];
        return;
    }
    i -= 262144;
    if (i < 262144) {                            // WW (256,1024) -> (1024,256)
        const int rr = i >> 10, cc = i & 1023;
        WWt[(size_t)cc * 256 + rr] = (bf16_t)WW[i];
        return;
    }
    i -= 262144;
    if (i < 65536) {                             // UfW (256,256) -> (256,256)
        const int rr = i >> 8, cc = i & 255;
        UfWt[(size_t)cc * 256 + rr] = (bf16_t)UfW[i];
        return;
    }
    i -= 65536;
    if (i < 196608) {                            // UiW (256,768) -> (768,256)
        const int rr = i / 768, cc = i - rr * 768;
        UiWt[(size_t)cc * 256 + rr] = (bf16_t)UiW[i];
    }
}

// ---------------- zero the dummy rows (1536 B = 384 f32 each) of both state buffers ----------------
__global__ __launch_bounds__(256) void k_zero(float* __restrict__ SA, float* __restrict__ SB)
{
    const int t = threadIdx.x;
    float* a = SA + (size_t)ZROW * 384;
    float* b = SB + (size_t)ZROW * 384;
    for (int i = t; i < 384; i += 256) { a[i] = 0.f; b[i] = 0.f; }
}

// ---------------- embed GEMM (measured-best round-3): 768 blocks x 256 thr ----------------
__global__ __launch_bounds__(256) void k_embed(
    const int* __restrict__ tok1, const int* __restrict__ tok2,
    const bf16_t* __restrict__ Ebf, const bf16_t* __restrict__ linWt,
    const float* __restrict__ linb, bf16_t* __restrict__ xout)
{
    __shared__ int toff[64][SS];
    const int t = threadIdx.x;
    const int m0 = blockIdx.x * 64;
    {
        const int lr = t >> 2, s = t & 3;
        const int m = m0 + lr;
        const int e = (m >= LN) ? 1 : 0;
        const int rrow = m - e * LN;
        const int* tok = e ? tok2 : tok1;
        toff[lr][s] = tok[(size_t)rrow * SS + s] * HH;
    }
    __syncthreads();
    const int lane = t & 63, w = t >> 6;
    const int wm = w >> 1, wn = w & 1;
    const int r = lane & 15, kg = lane >> 4;
    const int lr0 = wm * 32 + r, lr1 = lr0 + 16;
    const bf16_t* bp[8];
    #pragma unroll
    for (int j = 0; j < 8; ++j)
        bp[j] = linWt + (size_t)(wn * 128 + j * 16 + r) * 1024 + kg * 8;

    const f32x4 zero = {0.f, 0.f, 0.f, 0.f};
    f32x4 acc[2][8];
    #pragma unroll
    for (int mi = 0; mi < 2; ++mi)
        #pragma unroll
        for (int j = 0; j < 8; ++j) acc[mi][j] = zero;

    for (int k0 = 0; k0 < 1024; k0 += 32) {
        const int s = k0 >> 8, off = (k0 & 255) + kg * 8;
        const bf16x8 a0 = *(const bf16x8*)(Ebf + (size_t)toff[lr0][s] + off);
        const bf16x8 a1 = *(const bf16x8*)(Ebf + (size_t)toff[lr1][s] + off);
        #pragma unroll
        for (int j = 0; j < 8; ++j) {
            const bf16x8 b = *(const bf16x8*)bp[j];
            acc[0][j] = __builtin_amdgcn_mfma_f32_16x16x32_bf16(a0, b, acc[0][j], 0, 0, 0);
            acc[1][j] = __builtin_amdgcn_mfma_f32_16x16x32_bf16(a1, b, acc[1][j], 0, 0, 0);
            bp[j] += 32;
        }
    }
    const int crow = m0 + wm * 32 + kg * 4;
    #pragma unroll
    for (int j = 0; j < 8; ++j) {
        const int ccol = wn * 128 + j * 16 + r;
        const float bv = linb[ccol];
        #pragma unroll
        for (int mi = 0; mi < 2; ++mi)
            #pragma unroll
            for (int jj = 0; jj < 4; ++jj)
                xout[(size_t)(crow + mi * 16 + jj) * HH + ccol] =
                    (bf16_t)(acc[mi][j][jj] + bv);
    }
}

// ---------------- fused step kernel: all-bf16 packed state (1536 B rows) ----------------
// 256 blocks x 512 thr (8 waves), 16 rows/block. Gather loads overlap MFMA GEMMs.
__global__ __launch_bounds__(512, 2) void k_step(
    const bf16_t* __restrict__ xbf,
    const int* __restrict__ idx1, const int* __restrict__ idx2, const int l,
    const bf16_t* __restrict__ UfWt, const float* __restrict__ Ufb,
    const bf16_t* __restrict__ UiWt, const float* __restrict__ Uib,
    const bf16_t* __restrict__ WWt, const float* __restrict__ Wb,
    const char* __restrict__ Sprev, char* __restrict__ Snext)
{
    __shared__ __align__(16) bf16_t WxL[16 * 1024];   // 32 KB
    __shared__ __align__(16) bf16_t iuoL[16 * 768];   // 24 KB
    __shared__ __align__(16) bf16_t hsumL[16 * 256];  // 8 KB (hsum, later h_next; swizzled)

    const int t = threadIdx.x;
    const int bid = blockIdx.x;
    const int x  = bid & 7;                 // XCD id (round-robin dispatch)
    const int e  = x >> 2;                  // XCD 0-3 -> enc0, 4-7 -> enc1
    const int n0 = ((bid >> 3) * 4 + (x & 3)) * 16;
    const int g0 = e * NN + n0;
    const int lane = t & 63, w = t >> 6;
    const int r = lane & 15, kg = lane >> 4;
    const f32x4 zero = {0.f, 0.f, 0.f, 0.f};

    // gather identity: this thread owns (row rr, 16B slice sl)
    const int rr = t >> 5, sl = t & 31;
    const int ss = (sl + 4 * (rr & 7)) & 31;         // swizzled slice

    int ch[KK];
    {
        const int* idxp = (e ? idx2 : idx1) + ((size_t)l * NN + n0 + rr) * KK;
        const int4 i0 = *(const int4*)idxp;
        const int4 i1 = *(const int4*)(idxp + 4);
        ch[0] = i0.x; ch[1] = i0.y; ch[2] = i0.z; ch[3] = i0.w;
        ch[4] = i1.x; ch[5] = i1.y; ch[6] = i1.z; ch[7] = i1.w;
        #pragma unroll
        for (int k = 0; k < KK; ++k)
            ch[k] = (ch[k] >= 1) ? (e * NN + ch[k] - 1) : ZROW;
    }

    // ---- ph0: issue h gathers (consumed after Wx GEMM) ----
    bf16x8 hv[KK];
    #pragma unroll
    for (int k = 0; k < KK; ++k)
        hv[k] = *(const bf16x8*)(Sprev + (size_t)ch[k] * SROW + sl * 16);

    // ---- ph0b: x-row prefetch ----
    const bf16_t* xrow = xbf + ((size_t)e * LN + (size_t)l * NN + n0 + r) * HH + kg * 8;
    bf16x8 aWx[8];
    #pragma unroll
    for (int k = 0; k < 8; ++k) aWx[k] = *(const bf16x8*)(xrow + k * 32);

    // ---- ph1: Wx = x_l @ WW + Wb  (wave w -> col tiles 8w..8w+7) ----
    {
        const bf16_t* bw[8];
        #pragma unroll
        for (int j = 0; j < 8; ++j)
            bw[j] = WWt + (size_t)((8 * w + j) * 16 + r) * HH + kg * 8;
        f32x4 acc[8];
        #pragma unroll
        for (int j = 0; j < 8; ++j) acc[j] = zero;
        #pragma unroll
        for (int k = 0; k < 8; ++k) {
            #pragma unroll
            for (int j = 0; j < 8; ++j) {
                const bf16x8 b = *(const bf16x8*)bw[j];
                acc[j] = __builtin_amdgcn_mfma_f32_16x16x32_bf16(aWx[k], b, acc[j], 0, 0, 0);
                bw[j] += 32;
            }
        }
        #pragma unroll
        for (int j = 0; j < 8; ++j) {
            const int col = (8 * w + j) * 16 + r;
            const float bv = Wb[col];
            #pragma unroll
            for (int jj = 0; jj < 4; ++jj)
                WxL[(size_t)(kg * 4 + jj) * 1024 + col] = (bf16_t)(acc[j][jj] + bv);
        }
    }

    // ---- ph1b: consume h -> hsum -> LDS ----
    {
        float hs[8] = {0.f, 0.f, 0.f, 0.f, 0.f, 0.f, 0.f, 0.f};
        #pragma unroll
        for (int k = 0; k < KK; ++k) {
            #pragma unroll
            for (int j = 0; j < 8; ++j) hs[j] += (float)hv[k][j];
        }
        bf16x8 o;
        #pragma unroll
        for (int j = 0; j < 8; ++j) o[j] = (bf16_t)hs[j];
        *(bf16x8*)(hsumL + rr * 256 + ss * 8) = o;
    }
    __syncthreads();   // SYNC1: WxL + hsumL visible

    // ---- ph2: issue c/Hf gathers (consumed after iuo GEMM) ----
    bf16x8 cv[KK], fv[KK];
    #pragma unroll
    for (int k = 0; k < KK; ++k) {
        const char* row = Sprev + (size_t)ch[k] * SROW;
        fv[k] = *(const bf16x8*)(row + 512 + sl * 16);
        cv[k] = *(const bf16x8*)(row + 1024 + sl * 16);
    }

    // ---- ph3: iuo = hsum @ UiW + Uib  (wave w -> col tiles 6w..6w+5) ----
    {
        const bf16_t* bu[6];
        #pragma unroll
        for (int j = 0; j < 6; ++j)
            bu[j] = UiWt + (size_t)((6 * w + j) * 16 + r) * HH + kg * 8;
        f32x4 acc[6];
        #pragma unroll
        for (int j = 0; j < 6; ++j) acc[j] = zero;
        for (int k0 = 0; k0 < HH; k0 += 32) {
            const int sa = (((k0 >> 3) + kg) + 4 * (r & 7)) & 31;
            const bf16x8 a = *(const bf16x8*)(hsumL + r * 256 + sa * 8);
            #pragma unroll
            for (int j = 0; j < 6; ++j) {
                const bf16x8 b = *(const bf16x8*)bu[j];
                acc[j] = __builtin_amdgcn_mfma_f32_16x16x32_bf16(a, b, acc[j], 0, 0, 0);
                bu[j] += 32;
            }
        }
        #pragma unroll
        for (int j = 0; j < 6; ++j) {
            const int col = (6 * w + j) * 16 + r;
            const float bv = Uib[col];
            #pragma unroll
            for (int jj = 0; jj < 4; ++jj)
                iuoL[(size_t)(kg * 4 + jj) * 768 + col] = (bf16_t)(acc[j][jj] + bv);
        }
    }

    // ---- ph3b: consume c/Hf -> ba (registers) ----
    float ba[8] = {0.f, 0.f, 0.f, 0.f, 0.f, 0.f, 0.f, 0.f};
    {
        float wf[8];
        const bf16x8 wv = *(const bf16x8*)(WxL + (size_t)rr * 1024 + sl * 8);
        #pragma unroll
        for (int j = 0; j < 8; ++j) wf[j] = (float)wv[j];
        #pragma unroll
        for (int k = 0; k < KK; ++k) {
            #pragma unroll
            for (int j = 0; j < 8; ++j) {
                const float fk = sigmoidf_(wf[j] + (float)fv[k][j]);
                ba[j] = fmaf(fk, (float)cv[k][j], ba[j]);
            }
        }
    }
    __syncthreads();   // SYNC2: iuoL visible; hsum reads done

    // ---- ph4: gates, (rr,sl) slice mapping, coalesced packed stores ----
    {
        const bf16x8 wiv = *(const bf16x8*)(WxL + (size_t)rr * 1024 + 256 + sl * 8);
        const bf16x8 wuv = *(const bf16x8*)(WxL + (size_t)rr * 1024 + 512 + sl * 8);
        const bf16x8 wov = *(const bf16x8*)(WxL + (size_t)rr * 1024 + 768 + sl * 8);
        const bf16x8 iv  = *(const bf16x8*)(iuoL + (size_t)rr * 768 + sl * 8);
        const bf16x8 uv  = *(const bf16x8*)(iuoL + (size_t)rr * 768 + 256 + sl * 8);
        const bf16x8 ov  = *(const bf16x8*)(iuoL + (size_t)rr * 768 + 512 + sl * 8);
        bf16x8 ncb, nhb;
        #pragma unroll
        for (int j = 0; j < 8; ++j) {
            const float ig = sigmoidf_((float)iv[j] + (float)wiv[j]);
            const float ug = tanhf((float)uv[j] + (float)wuv[j]);
            const float og = sigmoidf_((float)ov[j] + (float)wov[j]);
            const float nc = fmaf(ig, ug, ba[j]);
            ncb[j] = (bf16_t)nc;
            nhb[j] = (bf16_t)(og * tanhf(nc));
        }
        char* rowN = Snext + (size_t)(g0 + rr) * SROW;
        *(bf16x8*)(rowN + sl * 16) = nhb;
        *(bf16x8*)(rowN + 1024 + sl * 16) = ncb;
        *(bf16x8*)(hsumL + rr * 256 + ss * 8) = nhb;   // h_next for Hf GEMM
    }

    if (l < LL - 1) {
        __syncthreads();   // SYNC3: h_next visible
        // ---- ph5: Hf_next = h_next @ UfW + Ufb (wave w -> tiles 2w, 2w+1) ----
        const int ct0 = 2 * w;
        const bf16_t* bq0 = UfWt + (size_t)(ct0 * 16 + r) * HH + kg * 8;
        const bf16_t* bq1 = bq0 + (size_t)16 * HH;
        f32x4 ac0 = zero, ac1 = zero;
        for (int k0 = 0; k0 < HH; k0 += 32) {
            const int sa = (((k0 >> 3) + kg) + 4 * (r & 7)) & 31;
            const bf16x8 a = *(const bf16x8*)(hsumL + r * 256 + sa * 8);
            const bf16x8 b0 = *(const bf16x8*)bq0;
            const bf16x8 b1 = *(const bf16x8*)bq1;
            ac0 = __builtin_amdgcn_mfma_f32_16x16x32_bf16(a, b0, ac0, 0, 0, 0);
            ac1 = __builtin_amdgcn_mfma_f32_16x16x32_bf16(a, b1, ac1, 0, 0, 0);
            bq0 += 32; bq1 += 32;
        }
        const int c0 = ct0 * 16 + r, c1 = c0 + 16;
        const float bv0 = Ufb[c0], bv1 = Ufb[c1];
        #pragma unroll
        for (int jj = 0; jj < 4; ++jj) {
            bf16_t* fr = (bf16_t*)(Snext + (size_t)(g0 + kg * 4 + jj) * SROW + 512);
            fr[c0] = (bf16_t)(ac0[jj] + bv0);
            fr[c1] = (bf16_t)(ac1[jj] + bv1);
        }
    }
}

// ---------------- siamese head (h read from packed state, offset 0) ----------------
__global__ __launch_bounds__(256) void k_final(
    const char* __restrict__ Sfin, const bf16_t* __restrict__ xbf,
    const float* __restrict__ dW, const float* __restrict__ db,
    const float* __restrict__ oW, const float* __restrict__ ob,
    float* __restrict__ out)
{
    __shared__ __align__(16) float ad[8][HH];
    __shared__ __align__(16) float xx[8][512];
    const int t = threadIdx.x;
    const int n0 = blockIdx.x * 8;
    const size_t xoff1 = (size_t)(LL - 1) * NN * HH;
    const size_t xoff2 = (size_t)LN * HH + xoff1;
    #pragma unroll
    for (int rr = 0; rr < 8; ++rr) {
        const int n = n0 + rr;
        const float h1 = (float)((const bf16_t*)(Sfin + (size_t)n * SROW))[t]
                       + (float)xbf[xoff1 + (size_t)n * HH + t];
        const float h2 = (float)((const bf16_t*)(Sfin + (size_t)(NN + n) * SROW))[t]
                       + (float)xbf[xoff2 + (size_t)n * HH + t];
        ad[rr][t] = fabsf(h1 - h2);
    }
    __syncthreads();
    float a0[8], a1[8];
    #pragma unroll
    for (int rr = 0; rr < 8; ++rr) { a0[rr] = 0.f; a1[rr] = 0.f; }
    for (int k = 0; k < HH; k += 4) {
        #pragma unroll
        for (int kk = 0; kk < 4; ++kk) {
            const float b0 = dW[(size_t)(k + kk) * 512 + t];
            const float b1 = dW[(size_t)(k + kk) * 512 + 256 + t];
            #pragma unroll
            for (int rr = 0; rr < 8; ++rr) {
                const float av = ad[rr][k + kk];
                a0[rr] = fmaf(av, b0, a0[rr]);
                a1[rr] = fmaf(av, b1, a1[rr]);
            }
        }
    }
    const float db0 = db[t], db1 = db[256 + t];
    #pragma unroll
    for (int rr = 0; rr < 8; ++rr) {
        xx[rr][t] = tanhf(a0[rr] + db0);
        xx[rr][256 + t] = tanhf(a1[rr] + db1);
    }
    __syncthreads();
    const int w = t >> 6, lane = t & 63;
    for (int rr = w; rr < 8; rr += 4) {
        float p0 = 0.f, p1 = 0.f;
        for (int k = lane; k < 512; k += 64) {
            const float xv = xx[rr][k];
            p0 = fmaf(xv, oW[2 * k + 0], p0);
            p1 = fmaf(xv, oW[2 * k + 1], p1);
        }
        #pragma unroll
        for (int off = 32; off > 0; off >>= 1) {
            p0 += __shfl_down(p0, off);
            p1 += __shfl_down(p1, off);
        }
        if (lane == 0) {
            const float l0 = p0 + ob[0], l1 = p1 + ob[1];
            const float mx = fmaxf(l0, l1);
            const float e0 = expf(l0 - mx), e1 = expf(l1 - mx);
            const float inv = 1.f / (e0 + e1);
            out[(size_t)(n0 + rr) * 2 + 0] = e0 * inv;
            out[(size_t)(n0 + rr) * 2 + 1] = e1 * inv;
        }
    }
}

extern "C" void kernel_launch(void* const* d_in, const int* in_sizes, int n_in,
                              void* d_out, int out_size, void* d_ws, size_t ws_size,
                              hipStream_t stream) {
    (void)in_sizes; (void)n_in; (void)out_size; (void)ws_size;
    const int*   tok1 = (const int*)d_in[0];
    const int*   idx1 = (const int*)d_in[1];
    const int*   tok2 = (const int*)d_in[2];
    const int*   idx2 = (const int*)d_in[3];
    const float* E    = (const float*)d_in[4];
    const float* linW = (const float*)d_in[5];
    const float* linb = (const float*)d_in[6];
    const float* UfW  = (const float*)d_in[7];
    const float* Ufb  = (const float*)d_in[8];
    const float* UiW  = (const float*)d_in[9];
    const float* Uib  = (const float*)d_in[10];
    const float* WW   = (const float*)d_in[11];
    const float* Wb   = (const float*)d_in[12];
    const float* dW   = (const float*)d_in[13];
    const float* db   = (const float*)d_in[14];
    const float* oW   = (const float*)d_in[15];
    const float* ob   = (const float*)d_in[16];
    float* out = (float*)d_out;

    // ws: xbf | UNION{ Ebf (dead after embed) | SA SB packed state } | weights  (~52.3 MB)
    bf16_t* xbf = (bf16_t*)d_ws;                        // 12,582,912 elems (25,165,824 B)
    char*   uni = (char*)(xbf + (size_t)12582912);
    bf16_t* Ebf = (bf16_t*)uni;                         // 25.6 MB
    char*   SA  = uni;                                  // 4097 rows x 1536 B = 6,292,992 B
    char*   SB  = uni + 6292992;                        // total 12.59 MB < 25.6 MB
    bf16_t* linWt = (bf16_t*)(uni + 25600000);          // 262,144
    bf16_t* WWt   = linWt + (size_t)262144;             // 262,144
    bf16_t* UfWt  = WWt   + (size_t)262144;             // 65,536
    bf16_t* UiWt  = UfWt  + (size_t)65536;              // 196,608

    k_cvtE<<<2048, 256, 0, stream>>>(E, Ebf, VV * HH / 4);
    k_cvtW<<<3072, 256, 0, stream>>>(linW, WW, UfW, UiW, linWt, WWt, UfWt, UiWt);

    k_embed<<<768, 256, 0, stream>>>(tok1, tok2, Ebf, linWt, linb, xbf);

    // zero dummy rows AFTER embed (SA/SB alias the Ebf region)
    k_zero<<<1, 256, 0, stream>>>((float*)SA, (float*)SB);

    char *Sp = SA, *Sn = SB;
    for (int l = 0; l < LL; ++l) {
        // l==0: idx[0] all -1 -> all children = ZROW (zeroed) -> poison/alias safe
        k_step<<<256, 512, 0, stream>>>(xbf, idx1, idx2, l,
                                        UfWt, Ufb, UiWt, Uib, WWt, Wb, Sp, Sn);
        char* ts = Sp; Sp = Sn; Sn = ts;
    }

    k_final<<<NN / 8, 256, 0, stream>>>(Sp, xbf, dW, db, oW, ob, out);
}

// Round 15
// 698.804 us; speedup vs baseline: 1.1122x; 1.0040x over previous
//
#include <hip/hip_runtime.h>

#define LL 12
#define NN 2048
#define KK 8
#define SS 4
#define HH 256
#define LN (LL*NN)
#define VV 50000
#define ZROW 4096
#define SROW 1536   // bytes per packed state row: [h bf16 256 | Hf bf16 256 | c bf16 256]

typedef __bf16 bf16_t;
typedef __bf16 bf16x8 __attribute__((ext_vector_type(8)));
typedef __bf16 bf16x4v __attribute__((ext_vector_type(4)));
typedef float f32x4 __attribute__((ext_vector_type(4)));

__device__ __forceinline__ float sigmoidf_(float x) { return 1.f / (1.f + expf(-x)); }

// ---------------- E f32 -> bf16 ----------------
__global__ __launch_bounds__(256) void k_cvtE(const float* __restrict__ src,
                                              bf16_t* __restrict__ dst, int n4)
{
    int i = blockIdx.x * 256 + threadIdx.x;
    const int stride = gridDim.x * 256;
    for (; i < n4; i += stride) {
        const float4 v = ((const float4*)src)[i];
        bf16x4v o;
        o[0] = (bf16_t)v.x; o[1] = (bf16_t)v.y; o[2] = (bf16_t)v.z; o[3] = (bf16_t)v.w;
        ((bf16x4v*)dst)[i] = o;
    }
}

// ---------------- weight transposes (f32 (K,N) -> bf16 (N,K)) ----------------
__global__ __launch_bounds__(256) void k_cvtW(
    const float* __restrict__ linW, const float* __restrict__ WW,
    const float* __restrict__ UfW, const float* __restrict__ UiW,
    bf16_t* __restrict__ linWt, bf16_t* __restrict__ WWt,
    bf16_t* __restrict__ UfWt, bf16_t* __restrict__ UiWt)
{
    int i = blockIdx.x * 256 + threadIdx.x;      // total 786432
    if (i < 262144) {                            // linW (1024,256) -> (256,1024)
        const int rr = i >> 8, cc = i & 255;
        linWt[(size_t)cc * 1024 + rr] = (bf16_t)linW[i];
        return;
    }
    i -= 262144;
    if (i < 262144) {                            // WW (256,1024) -> (1024,256)
        const int rr = i >> 10, cc = i & 1023;
        WWt[(size_t)cc * 256 + rr] = (bf16_t)WW[i];
        return;
    }
    i -= 262144;
    if (i < 65536) {                             // UfW (256,256) -> (256,256)
        const int rr = i >> 8, cc = i & 255;
        UfWt[(size_t)cc * 256 + rr] = (bf16_t)UfW[i];
        return;
    }
    i -= 65536;
    if (i < 196608) {                            // UiW (256,768) -> (768,256)
        const int rr = i / 768, cc = i - rr * 768;
        UiWt[(size_t)cc * 256 + rr] = (bf16_t)UiW[i];
    }
}

// ---------------- zero the dummy rows (1536 B = 384 f32 each) of both state buffers ----------------
__global__ __launch_bounds__(256) void k_zero(float* __restrict__ SA, float* __restrict__ SB)
{
    const int t = threadIdx.x;
    float* a = SA + (size_t)ZROW * 384;
    float* b = SB + (size_t)ZROW * 384;
    for (int i = t; i < 384; i += 256) { a[i] = 0.f; b[i] = 0.f; }
}

// ---------------- fused embed + Wx precompute ----------------
// 768 blocks x 256 thr. Phase A = round-3 x-GEMM (unchanged math). Phase B: Wx = x@WW+Wb.
__global__ __launch_bounds__(256) void k_embedwx(
    const int* __restrict__ tok1, const int* __restrict__ tok2,
    const bf16_t* __restrict__ Ebf, const bf16_t* __restrict__ linWt,
    const float* __restrict__ linb,
    const bf16_t* __restrict__ WWt, const float* __restrict__ Wb,
    bf16_t* __restrict__ xsm, bf16_t* __restrict__ Wxs)
{
    __shared__ int toff[64][SS];
    __shared__ __align__(16) bf16_t xtile[64 * 256];   // 32 KB, rotate-swizzled
    const int t = threadIdx.x;
    const int m0 = blockIdx.x * 64;
    {
        const int lr = t >> 2, s = t & 3;
        const int m = m0 + lr;
        const int e = (m >= LN) ? 1 : 0;
        const int rrow = m - e * LN;
        const int* tok = e ? tok2 : tok1;
        toff[lr][s] = tok[(size_t)rrow * SS + s] * HH;
    }
    __syncthreads();
    const int lane = t & 63, w = t >> 6;
    const int wm = w >> 1, wn = w & 1;
    const int r = lane & 15, kg = lane >> 4;
    const int lr0 = wm * 32 + r, lr1 = lr0 + 16;
    const f32x4 zero = {0.f, 0.f, 0.f, 0.f};

    // ---- phase A: x = concat(E[tok]) @ linW (round-3 structure, unchanged) ----
    {
        const bf16_t* bp[8];
        #pragma unroll
        for (int j = 0; j < 8; ++j)
            bp[j] = linWt + (size_t)(wn * 128 + j * 16 + r) * 1024 + kg * 8;
        f32x4 acc[2][8];
        #pragma unroll
        for (int mi = 0; mi < 2; ++mi)
            #pragma unroll
            for (int j = 0; j < 8; ++j) acc[mi][j] = zero;

        for (int k0 = 0; k0 < 1024; k0 += 32) {
            const int s = k0 >> 8, off = (k0 & 255) + kg * 8;
            const bf16x8 a0 = *(const bf16x8*)(Ebf + (size_t)toff[lr0][s] + off);
            const bf16x8 a1 = *(const bf16x8*)(Ebf + (size_t)toff[lr1][s] + off);
            #pragma unroll
            for (int j = 0; j < 8; ++j) {
                const bf16x8 b = *(const bf16x8*)bp[j];
                acc[0][j] = __builtin_amdgcn_mfma_f32_16x16x32_bf16(a0, b, acc[0][j], 0, 0, 0);
                acc[1][j] = __builtin_amdgcn_mfma_f32_16x16x32_bf16(a1, b, acc[1][j], 0, 0, 0);
                bp[j] += 32;
            }
        }
        // store x-tile (bf16, bias applied) to LDS; l==11 rows also to xsm
        const int e0 = (m0 >= LN) ? 1 : 0;
        const int lblk = (m0 - e0 * LN) >> 11;
        const int nbase = m0 & (NN - 1);
        const int crowL = wm * 32 + kg * 4;
        #pragma unroll
        for (int j = 0; j < 8; ++j) {
            const int ccol = wn * 128 + j * 16 + r;
            const float bv = linb[ccol];
            #pragma unroll
            for (int mi = 0; mi < 2; ++mi) {
                #pragma unroll
                for (int jj = 0; jj < 4; ++jj) {
                    const int rowL = crowL + mi * 16 + jj;
                    const bf16_t val = (bf16_t)(acc[mi][j][jj] + bv);
                    const int ps = ((ccol >> 3) + rowL) & 31;
                    xtile[rowL * 256 + ps * 8 + (ccol & 7)] = val;
                    if (lblk == LL - 1)
                        xsm[((size_t)e0 * NN + nbase + rowL) * HH + ccol] = val;
                }
            }
        }
    }
    __syncthreads();

    // ---- phase B: Wx = x @ WW + Wb  (wave w -> cols w*256..w*256+255) ----
    for (int mp = 0; mp < 2; ++mp) {
        for (int nh = 0; nh < 2; ++nh) {
            f32x4 acc2[2][8];
            #pragma unroll
            for (int mi = 0; mi < 2; ++mi)
                #pragma unroll
                for (int nt = 0; nt < 8; ++nt) acc2[mi][nt] = zero;
            for (int k0 = 0; k0 < 8; ++k0) {
                const int row0 = mp * 32 + r, row1 = row0 + 16;
                const int sk = k0 * 4 + kg;
                const bf16x8 a0 = *(const bf16x8*)(xtile + row0 * 256 + ((sk + row0) & 31) * 8);
                const bf16x8 a1 = *(const bf16x8*)(xtile + row1 * 256 + ((sk + row1) & 31) * 8);
                #pragma unroll
                for (int nt = 0; nt < 8; ++nt) {
                    const bf16x8 b = *(const bf16x8*)(WWt +
                        (size_t)(w * 256 + (nh * 8 + nt) * 16 + r) * HH + k0 * 32 + kg * 8);
                    acc2[0][nt] = __builtin_amdgcn_mfma_f32_16x16x32_bf16(a0, b, acc2[0][nt], 0, 0, 0);
                    acc2[1][nt] = __builtin_amdgcn_mfma_f32_16x16x32_bf16(a1, b, acc2[1][nt], 0, 0, 0);
                }
            }
            #pragma unroll
            for (int nt = 0; nt < 8; ++nt) {
                const int col = w * 256 + (nh * 8 + nt) * 16 + r;
                const float bv = Wb[col];
                #pragma unroll
                for (int mi = 0; mi < 2; ++mi) {
                    #pragma unroll
                    for (int jj = 0; jj < 4; ++jj)
                        Wxs[(size_t)(m0 + mp * 32 + mi * 16 + kg * 4 + jj) * 1024 + col] =
                            (bf16_t)(acc2[mi][nt][jj] + bv);
                }
            }
        }
    }
}

// ---------------- step kernel v3: Wx precomputed; gathers issued at entry ----------------
// 256 blocks x 512 thr (8 waves), 16 rows/block.
__global__ __launch_bounds__(512, 2) void k_step2(
    const int* __restrict__ idx1, const int* __restrict__ idx2, const int l,
    const bf16_t* __restrict__ UfWt, const float* __restrict__ Ufb,
    const bf16_t* __restrict__ UiWt, const float* __restrict__ Uib,
    const bf16_t* __restrict__ Wxs,
    const char* __restrict__ Sprev, char* __restrict__ Snext)
{
    __shared__ __align__(16) bf16_t iuoL[16 * 768];   // 24 KB
    __shared__ __align__(16) bf16_t hsumL[16 * 256];  // 8 KB (hsum, later h_next; swizzled)

    const int t = threadIdx.x;
    const int bid = blockIdx.x;
    const int x  = bid & 7;
    const int e  = x >> 2;
    const int n0 = ((bid >> 3) * 4 + (x & 3)) * 16;
    const int g0 = e * NN + n0;
    const int lane = t & 63, w = t >> 6;
    const int r = lane & 15, kg = lane >> 4;
    const f32x4 zero = {0.f, 0.f, 0.f, 0.f};

    const int rr = t >> 5, sl = t & 31;
    const int ss = (sl + 4 * (rr & 7)) & 31;

    int ch[KK];
    {
        const int* idxp = (e ? idx2 : idx1) + ((size_t)l * NN + n0 + rr) * KK;
        const int4 i0 = *(const int4*)idxp;
        const int4 i1 = *(const int4*)(idxp + 4);
        ch[0] = i0.x; ch[1] = i0.y; ch[2] = i0.z; ch[3] = i0.w;
        ch[4] = i1.x; ch[5] = i1.y; ch[6] = i1.z; ch[7] = i1.w;
        #pragma unroll
        for (int k = 0; k < KK; ++k)
            ch[k] = (ch[k] >= 1) ? (e * NN + ch[k] - 1) : ZROW;
    }

    // ---- entry: issue ALL independent loads ----
    const bf16_t* wxp = Wxs + ((size_t)e * LN + (size_t)l * NN + n0 + rr) * 1024;
    const bf16x8 wfv = *(const bf16x8*)(wxp + sl * 8);
    const bf16x8 wiv = *(const bf16x8*)(wxp + 256 + sl * 8);
    const bf16x8 wuv = *(const bf16x8*)(wxp + 512 + sl * 8);
    const bf16x8 wov = *(const bf16x8*)(wxp + 768 + sl * 8);
    bf16x8 hv[KK], fv[KK], cv[KK];
    #pragma unroll
    for (int k = 0; k < KK; ++k) {
        const char* row = Sprev + (size_t)ch[k] * SROW;
        hv[k] = *(const bf16x8*)(row + sl * 16);
        fv[k] = *(const bf16x8*)(row + 512 + sl * 16);
        cv[k] = *(const bf16x8*)(row + 1024 + sl * 16);
    }

    // ---- hsum -> LDS ----
    {
        float hs[8] = {0.f, 0.f, 0.f, 0.f, 0.f, 0.f, 0.f, 0.f};
        #pragma unroll
        for (int k = 0; k < KK; ++k) {
            #pragma unroll
            for (int j = 0; j < 8; ++j) hs[j] += (float)hv[k][j];
        }
        bf16x8 o;
        #pragma unroll
        for (int j = 0; j < 8; ++j) o[j] = (bf16_t)hs[j];
        *(bf16x8*)(hsumL + rr * 256 + ss * 8) = o;
    }
    __syncthreads();   // SYNC1: hsumL visible

    // ---- iuo = hsum @ UiW + Uib ----
    {
        const bf16_t* bu[6];
        #pragma unroll
        for (int j = 0; j < 6; ++j)
            bu[j] = UiWt + (size_t)((6 * w + j) * 16 + r) * HH + kg * 8;
        f32x4 acc[6];
        #pragma unroll
        for (int j = 0; j < 6; ++j) acc[j] = zero;
        for (int k0 = 0; k0 < HH; k0 += 32) {
            const int sa = (((k0 >> 3) + kg) + 4 * (r & 7)) & 31;
            const bf16x8 a = *(const bf16x8*)(hsumL + r * 256 + sa * 8);
            #pragma unroll
            for (int j = 0; j < 6; ++j) {
                const bf16x8 b = *(const bf16x8*)bu[j];
                acc[j] = __builtin_amdgcn_mfma_f32_16x16x32_bf16(a, b, acc[j], 0, 0, 0);
                bu[j] += 32;
            }
        }
        #pragma unroll
        for (int j = 0; j < 6; ++j) {
            const int col = (6 * w + j) * 16 + r;
            const float bv = Uib[col];
            #pragma unroll
            for (int jj = 0; jj < 4; ++jj)
                iuoL[(size_t)(kg * 4 + jj) * 768 + col] = (bf16_t)(acc[j][jj] + bv);
        }
    }

    // ---- ba from c/Hf/Wf (registers) ----
    float ba[8] = {0.f, 0.f, 0.f, 0.f, 0.f, 0.f, 0.f, 0.f};
    {
        float wf[8];
        #pragma unroll
        for (int j = 0; j < 8; ++j) wf[j] = (float)wfv[j];
        #pragma unroll
        for (int k = 0; k < KK; ++k) {
            #pragma unroll
            for (int j = 0; j < 8; ++j) {
                const float fk = sigmoidf_(wf[j] + (float)fv[k][j]);
                ba[j] = fmaf(fk, (float)cv[k][j], ba[j]);
            }
        }
    }
    __syncthreads();   // SYNC2: iuoL visible; hsum reads done

    // ---- gates ----
    {
        const bf16x8 iv = *(const bf16x8*)(iuoL + (size_t)rr * 768 + sl * 8);
        const bf16x8 uv = *(const bf16x8*)(iuoL + (size_t)rr * 768 + 256 + sl * 8);
        const bf16x8 ov = *(const bf16x8*)(iuoL + (size_t)rr * 768 + 512 + sl * 8);
        bf16x8 ncb, nhb;
        #pragma unroll
        for (int j = 0; j < 8; ++j) {
            const float ig = sigmoidf_((float)iv[j] + (float)wiv[j]);
            const float ug = tanhf((float)uv[j] + (float)wuv[j]);
            const float og = sigmoidf_((float)ov[j] + (float)wov[j]);
            const float nc = fmaf(ig, ug, ba[j]);
            ncb[j] = (bf16_t)nc;
            nhb[j] = (bf16_t)(og * tanhf(nc));
        }
        char* rowN = Snext + (size_t)(g0 + rr) * SROW;
        *(bf16x8*)(rowN + sl * 16) = nhb;
        *(bf16x8*)(rowN + 1024 + sl * 16) = ncb;
        *(bf16x8*)(hsumL + rr * 256 + ss * 8) = nhb;
    }

    if (l < LL - 1) {
        __syncthreads();   // SYNC3: h_next visible
        const int ct0 = 2 * w;
        const bf16_t* bq0 = UfWt + (size_t)(ct0 * 16 + r) * HH + kg * 8;
        const bf16_t* bq1 = bq0 + (size_t)16 * HH;
        f32x4 ac0 = zero, ac1 = zero;
        for (int k0 = 0; k0 < HH; k0 += 32) {
            const int sa = (((k0 >> 3) + kg) + 4 * (r & 7)) & 31;
            const bf16x8 a = *(const bf16x8*)(hsumL + r * 256 + sa * 8);
            const bf16x8 b0 = *(const bf16x8*)bq0;
            const bf16x8 b1 = *(const bf16x8*)bq1;
            ac0 = __builtin_amdgcn_mfma_f32_16x16x32_bf16(a, b0, ac0, 0, 0, 0);
            ac1 = __builtin_amdgcn_mfma_f32_16x16x32_bf16(a, b1, ac1, 0, 0, 0);
            bq0 += 32; bq1 += 32;
        }
        const int c0 = ct0 * 16 + r, c1 = c0 + 16;
        const float bv0 = Ufb[c0], bv1 = Ufb[c1];
        #pragma unroll
        for (int jj = 0; jj < 4; ++jj) {
            bf16_t* fr = (bf16_t*)(Snext + (size_t)(g0 + kg * 4 + jj) * SROW + 512);
            fr[c0] = (bf16_t)(ac0[jj] + bv0);
            fr[c1] = (bf16_t)(ac1[jj] + bv1);
        }
    }
}

// ---------------- siamese head v2 (x from xsm slice) ----------------
__global__ __launch_bounds__(256) void k_final2(
    const char* __restrict__ Sfin, const bf16_t* __restrict__ xsm,
    const float* __restrict__ dW, const float* __restrict__ db,
    const float* __restrict__ oW, const float* __restrict__ ob,
    float* __restrict__ out)
{
    __shared__ __align__(16) float ad[8][HH];
    __shared__ __align__(16) float xx[8][512];
    const int t = threadIdx.x;
    const int n0 = blockIdx.x * 8;
    #pragma unroll
    for (int rr = 0; rr < 8; ++rr) {
        const int n = n0 + rr;
        const float h1 = (float)((const bf16_t*)(Sfin + (size_t)n * SROW))[t]
                       + (float)xsm[(size_t)n * HH + t];
        const float h2 = (float)((const bf16_t*)(Sfin + (size_t)(NN + n) * SROW))[t]
                       + (float)xsm[((size_t)NN + n) * HH + t];
        ad[rr][t] = fabsf(h1 - h2);
    }
    __syncthreads();
    float a0[8], a1[8];
    #pragma unroll
    for (int rr = 0; rr < 8; ++rr) { a0[rr] = 0.f; a1[rr] = 0.f; }
    for (int k = 0; k < HH; k += 4) {
        #pragma unroll
        for (int kk = 0; kk < 4; ++kk) {
            const float b0 = dW[(size_t)(k + kk) * 512 + t];
            const float b1 = dW[(size_t)(k + kk) * 512 + 256 + t];
            #pragma unroll
            for (int rr = 0; rr < 8; ++rr) {
                const float av = ad[rr][k + kk];
                a0[rr] = fmaf(av, b0, a0[rr]);
                a1[rr] = fmaf(av, b1, a1[rr]);
            }
        }
    }
    const float db0 = db[t], db1 = db[256 + t];
    #pragma unroll
    for (int rr = 0; rr < 8; ++rr) {
        xx[rr][t] = tanhf(a0[rr] + db0);
        xx[rr][256 + t] = tanhf(a1[rr] + db1);
    }
    __syncthreads();
    const int w = t >> 6, lane = t & 63;
    for (int rr = w; rr < 8; rr += 4) {
        float p0 = 0.f, p1 = 0.f;
        for (int k = lane; k < 512; k += 64) {
            const float xv = xx[rr][k];
            p0 = fmaf(xv, oW[2 * k + 0], p0);
            p1 = fmaf(xv, oW[2 * k + 1], p1);
        }
        #pragma unroll
        for (int off = 32; off > 0; off >>= 1) {
            p0 += __shfl_down(p0, off);
            p1 += __shfl_down(p1, off);
        }
        if (lane == 0) {
            const float l0 = p0 + ob[0], l1 = p1 + ob[1];
            const float mx = fmaxf(l0, l1);
            const float e0 = expf(l0 - mx), e1 = expf(l1 - mx);
            const float inv = 1.f / (e0 + e1);
            out[(size_t)(n0 + rr) * 2 + 0] = e0 * inv;
            out[(size_t)(n0 + rr) * 2 + 1] = e1 * inv;
        }
    }
}

// ================= fallback (round-14) kernels =================
__global__ __launch_bounds__(256) void k_embed(
    const int* __restrict__ tok1, const int* __restrict__ tok2,
    const bf16_t* __restrict__ Ebf, const bf16_t* __restrict__ linWt,
    const float* __restrict__ linb, bf16_t* __restrict__ xout)
{
    __shared__ int toff[64][SS];
    const int t = threadIdx.x;
    const int m0 = blockIdx.x * 64;
    {
        const int lr = t >> 2, s = t & 3;
        const int m = m0 + lr;
        const int e = (m >= LN) ? 1 : 0;
        const int rrow = m - e * LN;
        const int* tok = e ? tok2 : tok1;
        toff[lr][s] = tok[(size_t)rrow * SS + s] * HH;
    }
    __syncthreads();
    const int lane = t & 63, w = t >> 6;
    const int wm = w >> 1, wn = w & 1;
    const int r = lane & 15, kg = lane >> 4;
    const int lr0 = wm * 32 + r, lr1 = lr0 + 16;
    const bf16_t* bp[8];
    #pragma unroll
    for (int j = 0; j < 8; ++j)
        bp[j] = linWt + (size_t)(wn * 128 + j * 16 + r) * 1024 + kg * 8;
    const f32x4 zero = {0.f, 0.f, 0.f, 0.f};
    f32x4 acc[2][8];
    #pragma unroll
    for (int mi = 0; mi < 2; ++mi)
        #pragma unroll
        for (int j = 0; j < 8; ++j) acc[mi][j] = zero;
    for (int k0 = 0; k0 < 1024; k0 += 32) {
        const int s = k0 >> 8, off = (k0 & 255) + kg * 8;
        const bf16x8 a0 = *(const bf16x8*)(Ebf + (size_t)toff[lr0][s] + off);
        const bf16x8 a1 = *(const bf16x8*)(Ebf + (size_t)toff[lr1][s] + off);
        #pragma unroll
        for (int j = 0; j < 8; ++j) {
            const bf16x8 b = *(const bf16x8*)bp[j];
            acc[0][j] = __builtin_amdgcn_mfma_f32_16x16x32_bf16(a0, b, acc[0][j], 0, 0, 0);
            acc[1][j] = __builtin_amdgcn_mfma_f32_16x16x32_bf16(a1, b, acc[1][j], 0, 0, 0);
            bp[j] += 32;
        }
    }
    const int crow = m0 + wm * 32 + kg * 4;
    #pragma unroll
    for (int j = 0; j < 8; ++j) {
        const int ccol = wn * 128 + j * 16 + r;
        const float bv = linb[ccol];
        #pragma unroll
        for (int mi = 0; mi < 2; ++mi)
            #pragma unroll
            for (int jj = 0; jj < 4; ++jj)
                xout[(size_t)(crow + mi * 16 + jj) * HH + ccol] =
                    (bf16_t)(acc[mi][j][jj] + bv);
    }
}

__global__ __launch_bounds__(512, 2) void k_step(
    const bf16_t* __restrict__ xbf,
    const int* __restrict__ idx1, const int* __restrict__ idx2, const int l,
    const bf16_t* __restrict__ UfWt, const float* __restrict__ Ufb,
    const bf16_t* __restrict__ UiWt, const float* __restrict__ Uib,
    const bf16_t* __restrict__ WWt, const float* __restrict__ Wb,
    const char* __restrict__ Sprev, char* __restrict__ Snext)
{
    __shared__ __align__(16) bf16_t WxL[16 * 1024];
    __shared__ __align__(16) bf16_t iuoL[16 * 768];
    __shared__ __align__(16) bf16_t hsumL[16 * 256];
    const int t = threadIdx.x;
    const int bid = blockIdx.x;
    const int x  = bid & 7;
    const int e  = x >> 2;
    const int n0 = ((bid >> 3) * 4 + (x & 3)) * 16;
    const int g0 = e * NN + n0;
    const int lane = t & 63, w = t >> 6;
    const int r = lane & 15, kg = lane >> 4;
    const f32x4 zero = {0.f, 0.f, 0.f, 0.f};
    const int rr = t >> 5, sl = t & 31;
    const int ss = (sl + 4 * (rr & 7)) & 31;
    int ch[KK];
    {
        const int* idxp = (e ? idx2 : idx1) + ((size_t)l * NN + n0 + rr) * KK;
        const int4 i0 = *(const int4*)idxp;
        const int4 i1 = *(const int4*)(idxp + 4);
        ch[0] = i0.x; ch[1] = i0.y; ch[2] = i0.z; ch[3] = i0.w;
        ch[4] = i1.x; ch[5] = i1.y; ch[6] = i1.z; ch[7] = i1.w;
        #pragma unroll
        for (int k = 0; k < KK; ++k)
            ch[k] = (ch[k] >= 1) ? (e * NN + ch[k] - 1) : ZROW;
    }
    bf16x8 hv[KK];
    #pragma unroll
    for (int k = 0; k < KK; ++k)
        hv[k] = *(const bf16x8*)(Sprev + (size_t)ch[k] * SROW + sl * 16);
    const bf16_t* xrow = xbf + ((size_t)e * LN + (size_t)l * NN + n0 + r) * HH + kg * 8;
    bf16x8 aWx[8];
    #pragma unroll
    for (int k = 0; k < 8; ++k) aWx[k] = *(const bf16x8*)(xrow + k * 32);
    {
        const bf16_t* bw[8];
        #pragma unroll
        for (int j = 0; j < 8; ++j)
            bw[j] = WWt + (size_t)((8 * w + j) * 16 + r) * HH + kg * 8;
        f32x4 acc[8];
        #pragma unroll
        for (int j = 0; j < 8; ++j) acc[j] = zero;
        #pragma unroll
        for (int k = 0; k < 8; ++k) {
            #pragma unroll
            for (int j = 0; j < 8; ++j) {
                const bf16x8 b = *(const bf16x8*)bw[j];
                acc[j] = __builtin_amdgcn_mfma_f32_16x16x32_bf16(aWx[k], b, acc[j], 0, 0, 0);
                bw[j] += 32;
            }
        }
        #pragma unroll
        for (int j = 0; j < 8; ++j) {
            const int col = (8 * w + j) * 16 + r;
            const float bv = Wb[col];
            #pragma unroll
            for (int jj = 0; jj < 4; ++jj)
                WxL[(size_t)(kg * 4 + jj) * 1024 + col] = (bf16_t)(acc[j][jj] + bv);
        }
    }
    {
        float hs[8] = {0.f, 0.f, 0.f, 0.f, 0.f, 0.f, 0.f, 0.f};
        #pragma unroll
        for (int k = 0; k < KK; ++k) {
            #pragma unroll
            for (int j = 0; j < 8; ++j) hs[j] += (float)hv[k][j];
        }
        bf16x8 o;
        #pragma unroll
        for (int j = 0; j < 8; ++j) o[j] = (bf16_t)hs[j];
        *(bf16x8*)(hsumL + rr * 256 + ss * 8) = o;
    }
    __syncthreads();
    bf16x8 cv[KK], fvv[KK];
    #pragma unroll
    for (int k = 0; k < KK; ++k) {
        const char* row = Sprev + (size_t)ch[k] * SROW;
        fvv[k] = *(const bf16x8*)(row + 512 + sl * 16);
        cv[k]  = *(const bf16x8*)(row + 1024 + sl * 16);
    }
    {
        const bf16_t* bu[6];
        #pragma unroll
        for (int j = 0; j < 6; ++j)
            bu[j] = UiWt + (size_t)((6 * w + j) * 16 + r) * HH + kg * 8;
        f32x4 acc[6];
        #pragma unroll
        for (int j = 0; j < 6; ++j) acc[j] = zero;
        for (int k0 = 0; k0 < HH; k0 += 32) {
            const int sa = (((k0 >> 3) + kg) + 4 * (r & 7)) & 31;
            const bf16x8 a = *(const bf16x8*)(hsumL + r * 256 + sa * 8);
            #pragma unroll
            for (int j = 0; j < 6; ++j) {
                const bf16x8 b = *(const bf16x8*)bu[j];
                acc[j] = __builtin_amdgcn_mfma_f32_16x16x32_bf16(a, b, acc[j], 0, 0, 0);
                bu[j] += 32;
            }
        }
        #pragma unroll
        for (int j = 0; j < 6; ++j) {
            const int col = (6 * w + j) * 16 + r;
            const float bv = Uib[col];
            #pragma unroll
            for (int jj = 0; jj < 4; ++jj)
                iuoL[(size_t)(kg * 4 + jj) * 768 + col] = (bf16_t)(acc[j][jj] + bv);
        }
    }
    float ba[8] = {0.f, 0.f, 0.f, 0.f, 0.f, 0.f, 0.f, 0.f};
    {
        float wf[8];
        const bf16x8 wv = *(const bf16x8*)(WxL + (size_t)rr * 1024 + sl * 8);
        #pragma unroll
        for (int j = 0; j < 8; ++j) wf[j] = (float)wv[j];
        #pragma unroll
        for (int k = 0; k < KK; ++k) {
            #pragma unroll
            for (int j = 0; j < 8; ++j) {
                const float fk = sigmoidf_(wf[j] + (float)fvv[k][j]);
                ba[j] = fmaf(fk, (float)cv[k][j], ba[j]);
            }
        }
    }
    __syncthreads();
    {
        const bf16x8 wiv = *(const bf16x8*)(WxL + (size_t)rr * 1024 + 256 + sl * 8);
        const bf16x8 wuv = *(const bf16x8*)(WxL + (size_t)rr * 1024 + 512 + sl * 8);
        const bf16x8 wov = *(const bf16x8*)(WxL + (size_t)rr * 1024 + 768 + sl * 8);
        const bf16x8 iv  = *(const bf16x8*)(iuoL + (size_t)rr * 768 + sl * 8);
        const bf16x8 uv  = *(const bf16x8*)(iuoL + (size_t)rr * 768 + 256 + sl * 8);
        const bf16x8 ov  = *(const bf16x8*)(iuoL + (size_t)rr * 768 + 512 + sl * 8);
        bf16x8 ncb, nhb;
        #pragma unroll
        for (int j = 0; j < 8; ++j) {
            const float ig = sigmoidf_((float)iv[j] + (float)wiv[j]);
            const float ug = tanhf((float)uv[j] + (float)wuv[j]);
            const float og = sigmoidf_((float)ov[j] + (float)wov[j]);
            const float nc = fmaf(ig, ug, ba[j]);
            ncb[j] = (bf16_t)nc;
            nhb[j] = (bf16_t)(og * tanhf(nc));
        }
        char* rowN = Snext + (size_t)(g0 + rr) * SROW;
        *(bf16x8*)(rowN + sl * 16) = nhb;
        *(bf16x8*)(rowN + 1024 + sl * 16) = ncb;
        *(bf16x8*)(hsumL + rr * 256 + ss * 8) = nhb;
    }
    if (l < LL - 1) {
        __syncthreads();
        const int ct0 = 2 * w;
        const bf16_t* bq0 = UfWt + (size_t)(ct0 * 16 + r) * HH + kg * 8;
        const bf16_t* bq1 = bq0 + (size_t)16 * HH;
        f32x4 ac0 = zero, ac1 = zero;
        for (int k0 = 0; k0 < HH; k0 += 32) {
            const int sa = (((k0 >> 3) + kg) + 4 * (r & 7)) & 31;
            const bf16x8 a = *(const bf16x8*)(hsumL + r * 256 + sa * 8);
            const bf16x8 b0 = *(const bf16x8*)bq0;
            const bf16x8 b1 = *(const bf16x8*)bq1;
            ac0 = __builtin_amdgcn_mfma_f32_16x16x32_bf16(a, b0, ac0, 0, 0, 0);
            ac1 = __builtin_amdgcn_mfma_f32_16x16x32_bf16(a, b1, ac1, 0, 0, 0);
            bq0 += 32; bq1 += 32;
        }
        const int c0 = ct0 * 16 + r, c1 = c0 + 16;
        const float bv0 = Ufb[c0], bv1 = Ufb[c1];
        #pragma unroll
        for (int jj = 0; jj < 4; ++jj) {
            bf16_t* fr = (bf16_t*)(Snext + (size_t)(g0 + kg * 4 + jj) * SROW + 512);
            fr[c0] = (bf16_t)(ac0[jj] + bv0);
            fr[c1] = (bf16_t)(ac1[jj] + bv1);
        }
    }
}

__global__ __launch_bounds__(256) void k_final(
    const char* __restrict__ Sfin, const bf16_t* __restrict__ xbf,
    const float* __restrict__ dW, const float* __restrict__ db,
    const float* __restrict__ oW, const float* __restrict__ ob,
    float* __restrict__ out)
{
    __shared__ __align__(16) float ad[8][HH];
    __shared__ __align__(16) float xx[8][512];
    const int t = threadIdx.x;
    const int n0 = blockIdx.x * 8;
    const size_t xoff1 = (size_t)(LL - 1) * NN * HH;
    const size_t xoff2 = (size_t)LN * HH + xoff1;
    #pragma unroll
    for (int rr = 0; rr < 8; ++rr) {
        const int n = n0 + rr;
        const float h1 = (float)((const bf16_t*)(Sfin + (size_t)n * SROW))[t]
                       + (float)xbf[xoff1 + (size_t)n * HH + t];
        const float h2 = (float)((const bf16_t*)(Sfin + (size_t)(NN + n) * SROW))[t]
                       + (float)xbf[xoff2 + (size_t)n * HH + t];
        ad[rr][t] = fabsf(h1 - h2);
    }
    __syncthreads();
    float a0[8], a1[8];
    #pragma unroll
    for (int rr = 0; rr < 8; ++rr) { a0[rr] = 0.f; a1[rr] = 0.f; }
    for (int k = 0; k < HH; k += 4) {
        #pragma unroll
        for (int kk = 0; kk < 4; ++kk) {
            const float b0 = dW[(size_t)(k + kk) * 512 + t];
            const float b1 = dW[(size_t)(k + kk) * 512 + 256 + t];
            #pragma unroll
            for (int rr = 0; rr < 8; ++rr) {
                const float av = ad[rr][k + kk];
                a0[rr] = fmaf(av, b0, a0[rr]);
                a1[rr] = fmaf(av, b1, a1[rr]);
            }
        }
    }
    const float db0 = db[t], db1 = db[256 + t];
    #pragma unroll
    for (int rr = 0; rr < 8; ++rr) {
        xx[rr][t] = tanhf(a0[rr] + db0);
        xx[rr][256 + t] = tanhf(a1[rr] + db1);
    }
    __syncthreads();
    const int w = t >> 6, lane = t & 63;
    for (int rr = w; rr < 8; rr += 4) {
        float p0 = 0.f, p1 = 0.f;
        for (int k = lane; k < 512; k += 64) {
            const float xv = xx[rr][k];
            p0 = fmaf(xv, oW[2 * k + 0], p0);
            p1 = fmaf(xv, oW[2 * k + 1], p1);
        }
        #pragma unroll
        for (int off = 32; off > 0; off >>= 1) {
            p0 += __shfl_down(p0, off);
            p1 += __shfl_down(p1, off);
        }
        if (lane == 0) {
            const float l0 = p0 + ob[0], l1 = p1 + ob[1];
            const float mx = fmaxf(l0, l1);
            const float e0 = expf(l0 - mx), e1 = expf(l1 - mx);
            const float inv = 1.f / (e0 + e1);
            out[(size_t)(n0 + rr) * 2 + 0] = e0 * inv;
            out[(size_t)(n0 + rr) * 2 + 1] = e1 * inv;
        }
    }
}

extern "C" void kernel_launch(void* const* d_in, const int* in_sizes, int n_in,
                              void* d_out, int out_size, void* d_ws, size_t ws_size,
                              hipStream_t stream) {
    (void)in_sizes; (void)n_in; (void)out_size;
    const int*   tok1 = (const int*)d_in[0];
    const int*   idx1 = (const int*)d_in[1];
    const int*   tok2 = (const int*)d_in[2];
    const int*   idx2 = (const int*)d_in[3];
    const float* E    = (const float*)d_in[4];
    const float* linW = (const float*)d_in[5];
    const float* linb = (const float*)d_in[6];
    const float* UfW  = (const float*)d_in[7];
    const float* Ufb  = (const float*)d_in[8];
    const float* UiW  = (const float*)d_in[9];
    const float* Uib  = (const float*)d_in[10];
    const float* WW   = (const float*)d_in[11];
    const float* Wb   = (const float*)d_in[12];
    const float* dW   = (const float*)d_in[13];
    const float* db   = (const float*)d_in[14];
    const float* oW   = (const float*)d_in[15];
    const float* ob   = (const float*)d_in[16];
    float* out = (float*)d_out;

    const size_t NEED = 100663296ull + 25600000ull + 2097152ull + 1572864ull; // 129,933,312

    if (ws_size >= NEED) {
        // Wxs | UNION{ Ebf | SA SB } | xsm | weights
        bf16_t* Wxs = (bf16_t*)d_ws;                        // 100,663,296 B
        char*   uni = (char*)d_ws + 100663296;
        bf16_t* Ebf = (bf16_t*)uni;                         // 25.6 MB (dead after embed)
        char*   SA  = uni;                                  // 4097*1536 = 6,292,992 B
        char*   SB  = uni + 6292992;
        bf16_t* xsm = (bf16_t*)(uni + 25600000);            // 2,097,152 B
        bf16_t* linWt = (bf16_t*)(uni + 25600000 + 2097152);
        bf16_t* WWt   = linWt + (size_t)262144;
        bf16_t* UfWt  = WWt   + (size_t)262144;
        bf16_t* UiWt  = UfWt  + (size_t)65536;

        k_cvtE<<<2048, 256, 0, stream>>>(E, Ebf, VV * HH / 4);
        k_cvtW<<<3072, 256, 0, stream>>>(linW, WW, UfW, UiW, linWt, WWt, UfWt, UiWt);
        k_embedwx<<<768, 256, 0, stream>>>(tok1, tok2, Ebf, linWt, linb, WWt, Wb, xsm, Wxs);
        k_zero<<<1, 256, 0, stream>>>((float*)SA, (float*)SB);

        char *Sp = SA, *Sn = SB;
        for (int l = 0; l < LL; ++l) {
            k_step2<<<256, 512, 0, stream>>>(idx1, idx2, l, UfWt, Ufb, UiWt, Uib,
                                             Wxs, Sp, Sn);
            char* ts = Sp; Sp = Sn; Sn = ts;
        }
        k_final2<<<NN / 8, 256, 0, stream>>>(Sp, xsm, dW, db, oW, ob, out);
    } else {
        // fallback = round-14 path
        bf16_t* xbf = (bf16_t*)d_ws;                        // 25,165,824 B
        char*   uni = (char*)(xbf + (size_t)12582912);
        bf16_t* Ebf = (bf16_t*)uni;
        char*   SA  = uni;
        char*   SB  = uni + 6292992;
        bf16_t* linWt = (bf16_t*)(uni + 25600000);
        bf16_t* WWt   = linWt + (size_t)262144;
        bf16_t* UfWt  = WWt   + (size_t)262144;
        bf16_t* UiWt  = UfWt  + (size_t)65536;

        k_cvtE<<<2048, 256, 0, stream>>>(E, Ebf, VV * HH / 4);
        k_cvtW<<<3072, 256, 0, stream>>>(linW, WW, UfW, UiW, linWt, WWt, UfWt, UiWt);
        k_embed<<<768, 256, 0, stream>>>(tok1, tok2, Ebf, linWt, linb, xbf);
        k_zero<<<1, 256, 0, stream>>>((float*)SA, (float*)SB);

        char *Sp = SA, *Sn = SB;
        for (int l = 0; l < LL; ++l) {
            k_step<<<256, 512, 0, stream>>>(xbf, idx1, idx2, l,
                                            UfWt, Ufb, UiWt, Uib, WWt, Wb, Sp, Sn);
            char* ts = Sp; Sp = Sn; Sn = ts;
        }
        k_final<<<NN / 8, 256, 0, stream>>>(Sp, xbf, dW, db, oW, ob, out);
    }
}

// Round 16
// 657.150 us; speedup vs baseline: 1.1827x; 1.0634x over previous
//
#include <hip/hip_runtime.h>

#define LL 12
#define NN 2048
#define KK 8
#define SS 4
#define HH 256
#define LN (LL*NN)
#define VV 50000
#define ZROW 4096
#define SROW 1536   // bytes per packed state row: [h bf16 256 | Hf bf16 256 | c bf16 256]

typedef __bf16 bf16_t;
typedef __bf16 bf16x8 __attribute__((ext_vector_type(8)));
typedef __bf16 bf16x4v __attribute__((ext_vector_type(4)));
typedef float f32x4 __attribute__((ext_vector_type(4)));

__device__ __forceinline__ float sigmoidf_(float x) { return 1.f / (1.f + expf(-x)); }

// ---------------- E f32 -> bf16 ----------------
__global__ __launch_bounds__(256) void k_cvtE(const float* __restrict__ src,
                                              bf16_t* __restrict__ dst, int n4)
{
    int i = blockIdx.x * 256 + threadIdx.x;
    const int stride = gridDim.x * 256;
    for (; i < n4; i += stride) {
        const float4 v = ((const float4*)src)[i];
        bf16x4v o;
        o[0] = (bf16_t)v.x; o[1] = (bf16_t)v.y; o[2] = (bf16_t)v.z; o[3] = (bf16_t)v.w;
        ((bf16x4v*)dst)[i] = o;
    }
}

// ---------------- weight transposes (f32 (K,N) -> bf16 (N,K)) ----------------
__global__ __launch_bounds__(256) void k_cvtW(
    const float* __restrict__ linW, const float* __restrict__ WW,
    const float* __restrict__ UfW, const float* __restrict__ UiW,
    bf16_t* __restrict__ linWt, bf16_t* __restrict__ WWt,
    bf16_t* __restrict__ UfWt, bf16_t* __restrict__ UiWt)
{
    int i = blockIdx.x * 256 + threadIdx.x;      // total 786432
    if (i < 262144) {                            // linW (1024,256) -> (256,1024)
        const int rr = i >> 8, cc = i & 255;
        linWt[(size_t)cc * 1024 + rr] = (bf16_t)linW[i];
        return;
    }
    i -= 262144;
    if (i < 262144) {                            // WW (256,1024) -> (1024,256)
        const int rr = i >> 10, cc = i & 1023;
        WWt[(size_t)cc * 256 + rr] = (bf16_t)WW[i];
        return;
    }
    i -= 262144;
    if (i < 65536) {                             // UfW (256,256) -> (256,256)
        const int rr = i >> 8, cc = i & 255;
        UfWt[(size_t)cc * 256 + rr] = (bf16_t)UfW[i];
        return;
    }
    i -= 65536;
    if (i < 196608) {                            // UiW (256,768) -> (768,256)
        const int rr = i / 768, cc = i - rr * 768;
        UiWt[(size_t)cc * 256 + rr] = (bf16_t)UiW[i];
    }
}

// ---------------- zero the dummy rows (1536 B = 384 f32 each) of both state buffers ----------------
__global__ __launch_bounds__(256) void k_zero(float* __restrict__ SA, float* __restrict__ SB)
{
    const int t = threadIdx.x;
    float* a = SA + (size_t)ZROW * 384;
    float* b = SB + (size_t)ZROW * 384;
    for (int i = t; i < 384; i += 256) { a[i] = 0.f; b[i] = 0.f; }
}

// ---------------- embed GEMM (round-3 measured-best) + xsm slice write ----------------
__global__ __launch_bounds__(256) void k_embed(
    const int* __restrict__ tok1, const int* __restrict__ tok2,
    const bf16_t* __restrict__ Ebf, const bf16_t* __restrict__ linWt,
    const float* __restrict__ linb, bf16_t* __restrict__ xout,
    bf16_t* __restrict__ xsm)
{
    __shared__ int toff[64][SS];
    const int t = threadIdx.x;
    const int m0 = blockIdx.x * 64;
    {
        const int lr = t >> 2, s = t & 3;
        const int m = m0 + lr;
        const int e = (m >= LN) ? 1 : 0;
        const int rrow = m - e * LN;
        const int* tok = e ? tok2 : tok1;
        toff[lr][s] = tok[(size_t)rrow * SS + s] * HH;
    }
    __syncthreads();
    const int lane = t & 63, w = t >> 6;
    const int wm = w >> 1, wn = w & 1;
    const int r = lane & 15, kg = lane >> 4;
    const int lr0 = wm * 32 + r, lr1 = lr0 + 16;
    const bf16_t* bp[8];
    #pragma unroll
    for (int j = 0; j < 8; ++j)
        bp[j] = linWt + (size_t)(wn * 128 + j * 16 + r) * 1024 + kg * 8;

    const f32x4 zero = {0.f, 0.f, 0.f, 0.f};
    f32x4 acc[2][8];
    #pragma unroll
    for (int mi = 0; mi < 2; ++mi)
        #pragma unroll
        for (int j = 0; j < 8; ++j) acc[mi][j] = zero;

    for (int k0 = 0; k0 < 1024; k0 += 32) {
        const int s = k0 >> 8, off = (k0 & 255) + kg * 8;
        const bf16x8 a0 = *(const bf16x8*)(Ebf + (size_t)toff[lr0][s] + off);
        const bf16x8 a1 = *(const bf16x8*)(Ebf + (size_t)toff[lr1][s] + off);
        #pragma unroll
        for (int j = 0; j < 8; ++j) {
            const bf16x8 b = *(const bf16x8*)bp[j];
            acc[0][j] = __builtin_amdgcn_mfma_f32_16x16x32_bf16(a0, b, acc[0][j], 0, 0, 0);
            acc[1][j] = __builtin_amdgcn_mfma_f32_16x16x32_bf16(a1, b, acc[1][j], 0, 0, 0);
            bp[j] += 32;
        }
    }
    const int e0 = (m0 >= LN) ? 1 : 0;
    const int lblk = (m0 - e0 * LN) >> 11;           // block-uniform (2048 % 64 == 0)
    const int nbase = m0 & (NN - 1);
    const int crow = m0 + wm * 32 + kg * 4;
    const int lrow = wm * 32 + kg * 4;
    #pragma unroll
    for (int j = 0; j < 8; ++j) {
        const int ccol = wn * 128 + j * 16 + r;
        const float bv = linb[ccol];
        #pragma unroll
        for (int mi = 0; mi < 2; ++mi)
            #pragma unroll
            for (int jj = 0; jj < 4; ++jj) {
                const bf16_t val = (bf16_t)(acc[mi][j][jj] + bv);
                xout[(size_t)(crow + mi * 16 + jj) * HH + ccol] = val;
                if (lblk == LL - 1)
                    xsm[((size_t)e0 * NN + nbase + lrow + mi * 16 + jj) * HH + ccol] = val;
            }
    }
}

// ---------------- dedicated Wx GEMM: Wxs = xbf @ WW + Wb  (M=49152,K=256,N=1024) ----------------
// grid (4, 768) x 256 thr (2x2 waves); block tile 64 rows x 256 cols.
__global__ __launch_bounds__(256) void k_wx(
    const bf16_t* __restrict__ xbf, const bf16_t* __restrict__ WWt,
    const float* __restrict__ Wb, bf16_t* __restrict__ Wxs)
{
    const int n0 = blockIdx.x * 256;
    const int m0 = blockIdx.y * 64;
    const int t = threadIdx.x;
    const int lane = t & 63, w = t >> 6;
    const int wm = w >> 1, wn = w & 1;
    const int r = lane & 15, kg = lane >> 4;
    const int lr0 = wm * 32 + r, lr1 = lr0 + 16;
    const bf16_t* ap0 = xbf + (size_t)(m0 + lr0) * HH + kg * 8;
    const bf16_t* ap1 = xbf + (size_t)(m0 + lr1) * HH + kg * 8;
    const bf16_t* bp[8];
    #pragma unroll
    for (int j = 0; j < 8; ++j)
        bp[j] = WWt + (size_t)(n0 + wn * 128 + j * 16 + r) * HH + kg * 8;

    const f32x4 zero = {0.f, 0.f, 0.f, 0.f};
    f32x4 acc[2][8];
    #pragma unroll
    for (int mi = 0; mi < 2; ++mi)
        #pragma unroll
        for (int j = 0; j < 8; ++j) acc[mi][j] = zero;

    for (int k0 = 0; k0 < HH; k0 += 32) {
        const bf16x8 a0 = *(const bf16x8*)(ap0 + k0);
        const bf16x8 a1 = *(const bf16x8*)(ap1 + k0);
        #pragma unroll
        for (int j = 0; j < 8; ++j) {
            const bf16x8 b = *(const bf16x8*)bp[j];
            acc[0][j] = __builtin_amdgcn_mfma_f32_16x16x32_bf16(a0, b, acc[0][j], 0, 0, 0);
            acc[1][j] = __builtin_amdgcn_mfma_f32_16x16x32_bf16(a1, b, acc[1][j], 0, 0, 0);
            bp[j] += 32;
        }
    }
    const int crow = m0 + wm * 32 + kg * 4;
    #pragma unroll
    for (int j = 0; j < 8; ++j) {
        const int ccol = n0 + wn * 128 + j * 16 + r;
        const float bv = Wb[ccol];
        #pragma unroll
        for (int mi = 0; mi < 2; ++mi)
            #pragma unroll
            for (int jj = 0; jj < 4; ++jj)
                Wxs[(size_t)(crow + mi * 16 + jj) * 1024 + ccol] =
                    (bf16_t)(acc[mi][j][jj] + bv);
    }
}

// ---------------- step kernel v3: Wx precomputed; gathers issued at entry ----------------
// 256 blocks x 512 thr (8 waves), 16 rows/block.
__global__ __launch_bounds__(512, 2) void k_step2(
    const int* __restrict__ idx1, const int* __restrict__ idx2, const int l,
    const bf16_t* __restrict__ UfWt, const float* __restrict__ Ufb,
    const bf16_t* __restrict__ UiWt, const float* __restrict__ Uib,
    const bf16_t* __restrict__ Wxs,
    const char* __restrict__ Sprev, char* __restrict__ Snext)
{
    __shared__ __align__(16) bf16_t iuoL[16 * 768];   // 24 KB
    __shared__ __align__(16) bf16_t hsumL[16 * 256];  // 8 KB (hsum, later h_next; swizzled)

    const int t = threadIdx.x;
    const int bid = blockIdx.x;
    const int x  = bid & 7;
    const int e  = x >> 2;
    const int n0 = ((bid >> 3) * 4 + (x & 3)) * 16;
    const int g0 = e * NN + n0;
    const int lane = t & 63, w = t >> 6;
    const int r = lane & 15, kg = lane >> 4;
    const f32x4 zero = {0.f, 0.f, 0.f, 0.f};

    const int rr = t >> 5, sl = t & 31;
    const int ss = (sl + 4 * (rr & 7)) & 31;

    int ch[KK];
    {
        const int* idxp = (e ? idx2 : idx1) + ((size_t)l * NN + n0 + rr) * KK;
        const int4 i0 = *(const int4*)idxp;
        const int4 i1 = *(const int4*)(idxp + 4);
        ch[0] = i0.x; ch[1] = i0.y; ch[2] = i0.z; ch[3] = i0.w;
        ch[4] = i1.x; ch[5] = i1.y; ch[6] = i1.z; ch[7] = i1.w;
        #pragma unroll
        for (int k = 0; k < KK; ++k)
            ch[k] = (ch[k] >= 1) ? (e * NN + ch[k] - 1) : ZROW;
    }

    // ---- entry: issue ALL independent loads ----
    const bf16_t* wxp = Wxs + ((size_t)e * LN + (size_t)l * NN + n0 + rr) * 1024;
    const bf16x8 wfv = *(const bf16x8*)(wxp + sl * 8);
    const bf16x8 wiv = *(const bf16x8*)(wxp + 256 + sl * 8);
    const bf16x8 wuv = *(const bf16x8*)(wxp + 512 + sl * 8);
    const bf16x8 wov = *(const bf16x8*)(wxp + 768 + sl * 8);
    bf16x8 hv[KK], fv[KK], cv[KK];
    #pragma unroll
    for (int k = 0; k < KK; ++k) {
        const char* row = Sprev + (size_t)ch[k] * SROW;
        hv[k] = *(const bf16x8*)(row + sl * 16);
        fv[k] = *(const bf16x8*)(row + 512 + sl * 16);
        cv[k] = *(const bf16x8*)(row + 1024 + sl * 16);
    }

    // ---- hsum -> LDS ----
    {
        float hs[8] = {0.f, 0.f, 0.f, 0.f, 0.f, 0.f, 0.f, 0.f};
        #pragma unroll
        for (int k = 0; k < KK; ++k) {
            #pragma unroll
            for (int j = 0; j < 8; ++j) hs[j] += (float)hv[k][j];
        }
        bf16x8 o;
        #pragma unroll
        for (int j = 0; j < 8; ++j) o[j] = (bf16_t)hs[j];
        *(bf16x8*)(hsumL + rr * 256 + ss * 8) = o;
    }
    __syncthreads();   // SYNC1: hsumL visible

    // ---- iuo = hsum @ UiW + Uib ----
    {
        const bf16_t* bu[6];
        #pragma unroll
        for (int j = 0; j < 6; ++j)
            bu[j] = UiWt + (size_t)((6 * w + j) * 16 + r) * HH + kg * 8;
        f32x4 acc[6];
        #pragma unroll
        for (int j = 0; j < 6; ++j) acc[j] = zero;
        for (int k0 = 0; k0 < HH; k0 += 32) {
            const int sa = (((k0 >> 3) + kg) + 4 * (r & 7)) & 31;
            const bf16x8 a = *(const bf16x8*)(hsumL + r * 256 + sa * 8);
            #pragma unroll
            for (int j = 0; j < 6; ++j) {
                const bf16x8 b = *(const bf16x8*)bu[j];
                acc[j] = __builtin_amdgcn_mfma_f32_16x16x32_bf16(a, b, acc[j], 0, 0, 0);
                bu[j] += 32;
            }
        }
        #pragma unroll
        for (int j = 0; j < 6; ++j) {
            const int col = (6 * w + j) * 16 + r;
            const float bv = Uib[col];
            #pragma unroll
            for (int jj = 0; jj < 4; ++jj)
                iuoL[(size_t)(kg * 4 + jj) * 768 + col] = (bf16_t)(acc[j][jj] + bv);
        }
    }

    // ---- ba from c/Hf/Wf (registers) ----
    float ba[8] = {0.f, 0.f, 0.f, 0.f, 0.f, 0.f, 0.f, 0.f};
    {
        float wf[8];
        #pragma unroll
        for (int j = 0; j < 8; ++j) wf[j] = (float)wfv[j];
        #pragma unroll
        for (int k = 0; k < KK; ++k) {
            #pragma unroll
            for (int j = 0; j < 8; ++j) {
                const float fk = sigmoidf_(wf[j] + (float)fv[k][j]);
                ba[j] = fmaf(fk, (float)cv[k][j], ba[j]);
            }
        }
    }
    __syncthreads();   // SYNC2: iuoL visible; hsum reads done

    // ---- gates ----
    {
        const bf16x8 iv = *(const bf16x8*)(iuoL + (size_t)rr * 768 + sl * 8);
        const bf16x8 uv = *(const bf16x8*)(iuoL + (size_t)rr * 768 + 256 + sl * 8);
        const bf16x8 ov = *(const bf16x8*)(iuoL + (size_t)rr * 768 + 512 + sl * 8);
        bf16x8 ncb, nhb;
        #pragma unroll
        for (int j = 0; j < 8; ++j) {
            const float ig = sigmoidf_((float)iv[j] + (float)wiv[j]);
            const float ug = tanhf((float)uv[j] + (float)wuv[j]);
            const float og = sigmoidf_((float)ov[j] + (float)wov[j]);
            const float nc = fmaf(ig, ug, ba[j]);
            ncb[j] = (bf16_t)nc;
            nhb[j] = (bf16_t)(og * tanhf(nc));
        }
        char* rowN = Snext + (size_t)(g0 + rr) * SROW;
        *(bf16x8*)(rowN + sl * 16) = nhb;
        *(bf16x8*)(rowN + 1024 + sl * 16) = ncb;
        *(bf16x8*)(hsumL + rr * 256 + ss * 8) = nhb;
    }

    if (l < LL - 1) {
        __syncthreads();   // SYNC3: h_next visible
        const int ct0 = 2 * w;
        const bf16_t* bq0 = UfWt + (size_t)(ct0 * 16 + r) * HH + kg * 8;
        const bf16_t* bq1 = bq0 + (size_t)16 * HH;
        f32x4 ac0 = zero, ac1 = zero;
        for (int k0 = 0; k0 < HH; k0 += 32) {
            const int sa = (((k0 >> 3) + kg) + 4 * (r & 7)) & 31;
            const bf16x8 a = *(const bf16x8*)(hsumL + r * 256 + sa * 8);
            const bf16x8 b0 = *(const bf16x8*)bq0;
            const bf16x8 b1 = *(const bf16x8*)bq1;
            ac0 = __builtin_amdgcn_mfma_f32_16x16x32_bf16(a, b0, ac0, 0, 0, 0);
            ac1 = __builtin_amdgcn_mfma_f32_16x16x32_bf16(a, b1, ac1, 0, 0, 0);
            bq0 += 32; bq1 += 32;
        }
        const int c0 = ct0 * 16 + r, c1 = c0 + 16;
        const float bv0 = Ufb[c0], bv1 = Ufb[c1];
        #pragma unroll
        for (int jj = 0; jj < 4; ++jj) {
            bf16_t* fr = (bf16_t*)(Snext + (size_t)(g0 + kg * 4 + jj) * SROW + 512);
            fr[c0] = (bf16_t)(ac0[jj] + bv0);
            fr[c1] = (bf16_t)(ac1[jj] + bv1);
        }
    }
}

// ---------------- siamese head (x from xsm slice) ----------------
__global__ __launch_bounds__(256) void k_final2(
    const char* __restrict__ Sfin, const bf16_t* __restrict__ xsm,
    const float* __restrict__ dW, const float* __restrict__ db,
    const float* __restrict__ oW, const float* __restrict__ ob,
    float* __restrict__ out)
{
    __shared__ __align__(16) float ad[8][HH];
    __shared__ __align__(16) float xx[8][512];
    const int t = threadIdx.x;
    const int n0 = blockIdx.x * 8;
    #pragma unroll
    for (int rr = 0; rr < 8; ++rr) {
        const int n = n0 + rr;
        const float h1 = (float)((const bf16_t*)(Sfin + (size_t)n * SROW))[t]
                       + (float)xsm[(size_t)n * HH + t];
        const float h2 = (float)((const bf16_t*)(Sfin + (size_t)(NN + n) * SROW))[t]
                       + (float)xsm[((size_t)NN + n) * HH + t];
        ad[rr][t] = fabsf(h1 - h2);
    }
    __syncthreads();
    float a0[8], a1[8];
    #pragma unroll
    for (int rr = 0; rr < 8; ++rr) { a0[rr] = 0.f; a1[rr] = 0.f; }
    for (int k = 0; k < HH; k += 4) {
        #pragma unroll
        for (int kk = 0; kk < 4; ++kk) {
            const float b0 = dW[(size_t)(k + kk) * 512 + t];
            const float b1 = dW[(size_t)(k + kk) * 512 + 256 + t];
            #pragma unroll
            for (int rr = 0; rr < 8; ++rr) {
                const float av = ad[rr][k + kk];
                a0[rr] = fmaf(av, b0, a0[rr]);
                a1[rr] = fmaf(av, b1, a1[rr]);
            }
        }
    }
    const float db0 = db[t], db1 = db[256 + t];
    #pragma unroll
    for (int rr = 0; rr < 8; ++rr) {
        xx[rr][t] = tanhf(a0[rr] + db0);
        xx[rr][256 + t] = tanhf(a1[rr] + db1);
    }
    __syncthreads();
    const int w = t >> 6, lane = t & 63;
    for (int rr = w; rr < 8; rr += 4) {
        float p0 = 0.f, p1 = 0.f;
        for (int k = lane; k < 512; k += 64) {
            const float xv = xx[rr][k];
            p0 = fmaf(xv, oW[2 * k + 0], p0);
            p1 = fmaf(xv, oW[2 * k + 1], p1);
        }
        #pragma unroll
        for (int off = 32; off > 0; off >>= 1) {
            p0 += __shfl_down(p0, off);
            p1 += __shfl_down(p1, off);
        }
        if (lane == 0) {
            const float l0 = p0 + ob[0], l1 = p1 + ob[1];
            const float mx = fmaxf(l0, l1);
            const float e0 = expf(l0 - mx), e1 = expf(l1 - mx);
            const float inv = 1.f / (e0 + e1);
            out[(size_t)(n0 + rr) * 2 + 0] = e0 * inv;
            out[(size_t)(n0 + rr) * 2 + 1] = e1 * inv;
        }
    }
}

// ================= fallback (round-14) kernels =================
__global__ __launch_bounds__(512, 2) void k_step(
    const bf16_t* __restrict__ xbf,
    const int* __restrict__ idx1, const int* __restrict__ idx2, const int l,
    const bf16_t* __restrict__ UfWt, const float* __restrict__ Ufb,
    const bf16_t* __restrict__ UiWt, const float* __restrict__ Uib,
    const bf16_t* __restrict__ WWt, const float* __restrict__ Wb,
    const char* __restrict__ Sprev, char* __restrict__ Snext)
{
    __shared__ __align__(16) bf16_t WxL[16 * 1024];
    __shared__ __align__(16) bf16_t iuoL[16 * 768];
    __shared__ __align__(16) bf16_t hsumL[16 * 256];
    const int t = threadIdx.x;
    const int bid = blockIdx.x;
    const int x  = bid & 7;
    const int e  = x >> 2;
    const int n0 = ((bid >> 3) * 4 + (x & 3)) * 16;
    const int g0 = e * NN + n0;
    const int lane = t & 63, w = t >> 6;
    const int r = lane & 15, kg = lane >> 4;
    const f32x4 zero = {0.f, 0.f, 0.f, 0.f};
    const int rr = t >> 5, sl = t & 31;
    const int ss = (sl + 4 * (rr & 7)) & 31;
    int ch[KK];
    {
        const int* idxp = (e ? idx2 : idx1) + ((size_t)l * NN + n0 + rr) * KK;
        const int4 i0 = *(const int4*)idxp;
        const int4 i1 = *(const int4*)(idxp + 4);
        ch[0] = i0.x; ch[1] = i0.y; ch[2] = i0.z; ch[3] = i0.w;
        ch[4] = i1.x; ch[5] = i1.y; ch[6] = i1.z; ch[7] = i1.w;
        #pragma unroll
        for (int k = 0; k < KK; ++k)
            ch[k] = (ch[k] >= 1) ? (e * NN + ch[k] - 1) : ZROW;
    }
    bf16x8 hv[KK];
    #pragma unroll
    for (int k = 0; k < KK; ++k)
        hv[k] = *(const bf16x8*)(Sprev + (size_t)ch[k] * SROW + sl * 16);
    const bf16_t* xrow = xbf + ((size_t)e * LN + (size_t)l * NN + n0 + r) * HH + kg * 8;
    bf16x8 aWx[8];
    #pragma unroll
    for (int k = 0; k < 8; ++k) aWx[k] = *(const bf16x8*)(xrow + k * 32);
    {
        const bf16_t* bw[8];
        #pragma unroll
        for (int j = 0; j < 8; ++j)
            bw[j] = WWt + (size_t)((8 * w + j) * 16 + r) * HH + kg * 8;
        f32x4 acc[8];
        #pragma unroll
        for (int j = 0; j < 8; ++j) acc[j] = zero;
        #pragma unroll
        for (int k = 0; k < 8; ++k) {
            #pragma unroll
            for (int j = 0; j < 8; ++j) {
                const bf16x8 b = *(const bf16x8*)bw[j];
                acc[j] = __builtin_amdgcn_mfma_f32_16x16x32_bf16(aWx[k], b, acc[j], 0, 0, 0);
                bw[j] += 32;
            }
        }
        #pragma unroll
        for (int j = 0; j < 8; ++j) {
            const int col = (8 * w + j) * 16 + r;
            const float bv = Wb[col];
            #pragma unroll
            for (int jj = 0; jj < 4; ++jj)
                WxL[(size_t)(kg * 4 + jj) * 1024 + col] = (bf16_t)(acc[j][jj] + bv);
        }
    }
    {
        float hs[8] = {0.f, 0.f, 0.f, 0.f, 0.f, 0.f, 0.f, 0.f};
        #pragma unroll
        for (int k = 0; k < KK; ++k) {
            #pragma unroll
            for (int j = 0; j < 8; ++j) hs[j] += (float)hv[k][j];
        }
        bf16x8 o;
        #pragma unroll
        for (int j = 0; j < 8; ++j) o[j] = (bf16_t)hs[j];
        *(bf16x8*)(hsumL + rr * 256 + ss * 8) = o;
    }
    __syncthreads();
    bf16x8 cv[KK], fvv[KK];
    #pragma unroll
    for (int k = 0; k < KK; ++k) {
        const char* row = Sprev + (size_t)ch[k] * SROW;
        fvv[k] = *(const bf16x8*)(row + 512 + sl * 16);
        cv[k]  = *(const bf16x8*)(row + 1024 + sl * 16);
    }
    {
        const bf16_t* bu[6];
        #pragma unroll
        for (int j = 0; j < 6; ++j)
            bu[j] = UiWt + (size_t)((6 * w + j) * 16 + r) * HH + kg * 8;
        f32x4 acc[6];
        #pragma unroll
        for (int j = 0; j < 6; ++j) acc[j] = zero;
        for (int k0 = 0; k0 < HH; k0 += 32) {
            const int sa = (((k0 >> 3) + kg) + 4 * (r & 7)) & 31;
            const bf16x8 a = *(const bf16x8*)(hsumL + r * 256 + sa * 8);
            #pragma unroll
            for (int j = 0; j < 6; ++j) {
                const bf16x8 b = *(const bf16x8*)bu[j];
                acc[j] = __builtin_amdgcn_mfma_f32_16x16x32_bf16(a, b, acc[j], 0, 0, 0);
                bu[j] += 32;
            }
        }
        #pragma unroll
        for (int j = 0; j < 6; ++j) {
            const int col = (6 * w + j) * 16 + r;
            const float bv = Uib[col];
            #pragma unroll
            for (int jj = 0; jj < 4; ++jj)
                iuoL[(size_t)(kg * 4 + jj) * 768 + col] = (bf16_t)(acc[j][jj] + bv);
        }
    }
    float ba[8] = {0.f, 0.f, 0.f, 0.f, 0.f, 0.f, 0.f, 0.f};
    {
        float wf[8];
        const bf16x8 wv = *(const bf16x8*)(WxL + (size_t)rr * 1024 + sl * 8);
        #pragma unroll
        for (int j = 0; j < 8; ++j) wf[j] = (float)wv[j];
        #pragma unroll
        for (int k = 0; k < KK; ++k) {
            #pragma unroll
            for (int j = 0; j < 8; ++j) {
                const float fk = sigmoidf_(wf[j] + (float)fvv[k][j]);
                ba[j] = fmaf(fk, (float)cv[k][j], ba[j]);
            }
        }
    }
    __syncthreads();
    {
        const bf16x8 wiv = *(const bf16x8*)(WxL + (size_t)rr * 1024 + 256 + sl * 8);
        const bf16x8 wuv = *(const bf16x8*)(WxL + (size_t)rr * 1024 + 512 + sl * 8);
        const bf16x8 wov = *(const bf16x8*)(WxL + (size_t)rr * 1024 + 768 + sl * 8);
        const bf16x8 iv  = *(const bf16x8*)(iuoL + (size_t)rr * 768 + sl * 8);
        const bf16x8 uv  = *(const bf16x8*)(iuoL + (size_t)rr * 768 + 256 + sl * 8);
        const bf16x8 ov  = *(const bf16x8*)(iuoL + (size_t)rr * 768 + 512 + sl * 8);
        bf16x8 ncb, nhb;
        #pragma unroll
        for (int j = 0; j < 8; ++j) {
            const float ig = sigmoidf_((float)iv[j] + (float)wiv[j]);
            const float ug = tanhf((float)uv[j] + (float)wuv[j]);
            const float og = sigmoidf_((float)ov[j] + (float)wov[j]);
            const float nc = fmaf(ig, ug, ba[j]);
            ncb[j] = (bf16_t)nc;
            nhb[j] = (bf16_t)(og * tanhf(nc));
        }
        char* rowN = Snext + (size_t)(g0 + rr) * SROW;
        *(bf16x8*)(rowN + sl * 16) = nhb;
        *(bf16x8*)(rowN + 1024 + sl * 16) = ncb;
        *(bf16x8*)(hsumL + rr * 256 + ss * 8) = nhb;
    }
    if (l < LL - 1) {
        __syncthreads();
        const int ct0 = 2 * w;
        const bf16_t* bq0 = UfWt + (size_t)(ct0 * 16 + r) * HH + kg * 8;
        const bf16_t* bq1 = bq0 + (size_t)16 * HH;
        f32x4 ac0 = zero, ac1 = zero;
        for (int k0 = 0; k0 < HH; k0 += 32) {
            const int sa = (((k0 >> 3) + kg) + 4 * (r & 7)) & 31;
            const bf16x8 a = *(const bf16x8*)(hsumL + r * 256 + sa * 8);
            const bf16x8 b0 = *(const bf16x8*)bq0;
            const bf16x8 b1 = *(const bf16x8*)bq1;
            ac0 = __builtin_amdgcn_mfma_f32_16x16x32_bf16(a, b0, ac0, 0, 0, 0);
            ac1 = __builtin_amdgcn_mfma_f32_16x16x32_bf16(a, b1, ac1, 0, 0, 0);
            bq0 += 32; bq1 += 32;
        }
        const int c0 = ct0 * 16 + r, c1 = c0 + 16;
        const float bv0 = Ufb[c0], bv1 = Ufb[c1];
        #pragma unroll
        for (int jj = 0; jj < 4; ++jj) {
            bf16_t* fr = (bf16_t*)(Snext + (size_t)(g0 + kg * 4 + jj) * SROW + 512);
            fr[c0] = (bf16_t)(ac0[jj] + bv0);
            fr[c1] = (bf16_t)(ac1[jj] + bv1);
        }
    }
}

__global__ __launch_bounds__(256) void k_final(
    const char* __restrict__ Sfin, const bf16_t* __restrict__ xbf,
    const float* __restrict__ dW, const float* __restrict__ db,
    const float* __restrict__ oW, const float* __restrict__ ob,
    float* __restrict__ out)
{
    __shared__ __align__(16) float ad[8][HH];
    __shared__ __align__(16) float xx[8][512];
    const int t = threadIdx.x;
    const int n0 = blockIdx.x * 8;
    const size_t xoff1 = (size_t)(LL - 1) * NN * HH;
    const size_t xoff2 = (size_t)LN * HH + xoff1;
    #pragma unroll
    for (int rr = 0; rr < 8; ++rr) {
        const int n = n0 + rr;
        const float h1 = (float)((const bf16_t*)(Sfin + (size_t)n * SROW))[t]
                       + (float)xbf[xoff1 + (size_t)n * HH + t];
        const float h2 = (float)((const bf16_t*)(Sfin + (size_t)(NN + n) * SROW))[t]
                       + (float)xbf[xoff2 + (size_t)n * HH + t];
        ad[rr][t] = fabsf(h1 - h2);
    }
    __syncthreads();
    float a0[8], a1[8];
    #pragma unroll
    for (int rr = 0; rr < 8; ++rr) { a0[rr] = 0.f; a1[rr] = 0.f; }
    for (int k = 0; k < HH; k += 4) {
        #pragma unroll
        for (int kk = 0; kk < 4; ++kk) {
            const float b0 = dW[(size_t)(k + kk) * 512 + t];
            const float b1 = dW[(size_t)(k + kk) * 512 + 256 + t];
            #pragma unroll
            for (int rr = 0; rr < 8; ++rr) {
                const float av = ad[rr][k + kk];
                a0[rr] = fmaf(av, b0, a0[rr]);
                a1[rr] = fmaf(av, b1, a1[rr]);
            }
        }
    }
    const float db0 = db[t], db1 = db[256 + t];
    #pragma unroll
    for (int rr = 0; rr < 8; ++rr) {
        xx[rr][t] = tanhf(a0[rr] + db0);
        xx[rr][256 + t] = tanhf(a1[rr] + db1);
    }
    __syncthreads();
    const int w = t >> 6, lane = t & 63;
    for (int rr = w; rr < 8; rr += 4) {
        float p0 = 0.f, p1 = 0.f;
        for (int k = lane; k < 512; k += 64) {
            const float xv = xx[rr][k];
            p0 = fmaf(xv, oW[2 * k + 0], p0);
            p1 = fmaf(xv, oW[2 * k + 1], p1);
        }
        #pragma unroll
        for (int off = 32; off > 0; off >>= 1) {
            p0 += __shfl_down(p0, off);
            p1 += __shfl_down(p1, off);
        }
        if (lane == 0) {
            const float l0 = p0 + ob[0], l1 = p1 + ob[1];
            const float mx = fmaxf(l0, l1);
            const float e0 = expf(l0 - mx), e1 = expf(l1 - mx);
            const float inv = 1.f / (e0 + e1);
            out[(size_t)(n0 + rr) * 2 + 0] = e0 * inv;
            out[(size_t)(n0 + rr) * 2 + 1] = e1 * inv;
        }
    }
}

extern "C" void kernel_launch(void* const* d_in, const int* in_sizes, int n_in,
                              void* d_out, int out_size, void* d_ws, size_t ws_size,
                              hipStream_t stream) {
    (void)in_sizes; (void)n_in; (void)out_size;
    const int*   tok1 = (const int*)d_in[0];
    const int*   idx1 = (const int*)d_in[1];
    const int*   tok2 = (const int*)d_in[2];
    const int*   idx2 = (const int*)d_in[3];
    const float* E    = (const float*)d_in[4];
    const float* linW = (const float*)d_in[5];
    const float* linb = (const float*)d_in[6];
    const float* UfW  = (const float*)d_in[7];
    const float* Ufb  = (const float*)d_in[8];
    const float* UiW  = (const float*)d_in[9];
    const float* Uib  = (const float*)d_in[10];
    const float* WW   = (const float*)d_in[11];
    const float* Wb   = (const float*)d_in[12];
    const float* dW   = (const float*)d_in[13];
    const float* db   = (const float*)d_in[14];
    const float* oW   = (const float*)d_in[15];
    const float* ob   = (const float*)d_in[16];
    float* out = (float*)d_out;

    // main-path ws: xbf(25,165,824; SA/SB alias after k_wx) | Wxs(100,663,296; Ebf aliases)
    //               | xsm(2,097,152) | weights(1,572,864)  = 129,499,136 B
    const size_t NEED = 129499136ull;

    if (ws_size >= NEED) {
        bf16_t* xbf = (bf16_t*)d_ws;                        // 25,165,824 B
        char*   SA  = (char*)d_ws;                          // aliases xbf (dead after k_wx)
        char*   SB  = (char*)d_ws + 6292992;
        char*   r2  = (char*)d_ws + 25165824;
        bf16_t* Wxs = (bf16_t*)r2;                          // 100,663,296 B
        bf16_t* Ebf = (bf16_t*)r2;                          // aliases Wxs (dead after embed)
        bf16_t* xsm = (bf16_t*)(r2 + 100663296);            // 2,097,152 B
        bf16_t* linWt = (bf16_t*)(r2 + 100663296 + 2097152);
        bf16_t* WWt   = linWt + (size_t)262144;
        bf16_t* UfWt  = WWt   + (size_t)262144;
        bf16_t* UiWt  = UfWt  + (size_t)65536;

        k_cvtE<<<2048, 256, 0, stream>>>(E, Ebf, VV * HH / 4);
        k_cvtW<<<3072, 256, 0, stream>>>(linW, WW, UfW, UiW, linWt, WWt, UfWt, UiWt);
        k_embed<<<768, 256, 0, stream>>>(tok1, tok2, Ebf, linWt, linb, xbf, xsm);
        k_wx<<<dim3(4, 768), 256, 0, stream>>>(xbf, WWt, Wb, Wxs);   // xbf dead after this
        k_zero<<<1, 256, 0, stream>>>((float*)SA, (float*)SB);

        char *Sp = SA, *Sn = SB;
        for (int l = 0; l < LL; ++l) {
            k_step2<<<256, 512, 0, stream>>>(idx1, idx2, l, UfWt, Ufb, UiWt, Uib,
                                             Wxs, Sp, Sn);
            char* ts = Sp; Sp = Sn; Sn = ts;
        }
        k_final2<<<NN / 8, 256, 0, stream>>>(Sp, xsm, dW, db, oW, ob, out);
    } else {
        // fallback = round-14 path
        bf16_t* xbf = (bf16_t*)d_ws;                        // 25,165,824 B
        char*   uni = (char*)(xbf + (size_t)12582912);
        bf16_t* Ebf = (bf16_t*)uni;
        char*   SA  = uni;
        char*   SB  = uni + 6292992;
        bf16_t* linWt = (bf16_t*)(uni + 25600000);
        bf16_t* WWt   = linWt + (size_t)262144;
        bf16_t* UfWt  = WWt   + (size_t)262144;
        bf16_t* UiWt  = UfWt  + (size_t)65536;
        bf16_t* xsm_f = (bf16_t*)(uni + 25600000 - 4194304); // unused placeholder
        (void)xsm_f;

        k_cvtE<<<2048, 256, 0, stream>>>(E, Ebf, VV * HH / 4);
        k_cvtW<<<3072, 256, 0, stream>>>(linW, WW, UfW, UiW, linWt, WWt, UfWt, UiWt);
        // fallback embed: write xbf only (xsm points at xbf tail slice, unused by k_final)
        k_embed<<<768, 256, 0, stream>>>(tok1, tok2, Ebf, linWt, linb, xbf,
                                         xbf + (size_t)(LL - 1) * NN * HH);
        k_zero<<<1, 256, 0, stream>>>((float*)SA, (float*)SB);

        char *Sp = SA, *Sn = SB;
        for (int l = 0; l < LL; ++l) {
            k_step<<<256, 512, 0, stream>>>(xbf, idx1, idx2, l,
                                            UfWt, Ufb, UiWt, Uib, WWt, Wb, Sp, Sn);
            char* ts = Sp; Sp = Sn; Sn = ts;
        }
        k_final<<<NN / 8, 256, 0, stream>>>(Sp, xbf, dW, db, oW, ob, out);
    }
}

// Round 17
// 656.584 us; speedup vs baseline: 1.1837x; 1.0009x over previous
//
#include <hip/hip_runtime.h>

#define LL 12
#define NN 2048
#define KK 8
#define SS 4
#define HH 256
#define LN (LL*NN)
#define VV 50000
#define ZROW 4096
#define SROW 1536   // bytes per packed state row: [h bf16 256 | Hf bf16 256 | c bf16 256]

typedef __bf16 bf16_t;
typedef __bf16 bf16x8 __attribute__((ext_vector_type(8)));
typedef __bf16 bf16x4v __attribute__((ext_vector_type(4)));
typedef float f32x4 __attribute__((ext_vector_type(4)));

__device__ __forceinline__ float sigmoidf_(float x) { return 1.f / (1.f + expf(-x)); }

// ---------------- E f32 -> bf16 ----------------
__global__ __launch_bounds__(256) void k_cvtE(const float* __restrict__ src,
                                              bf16_t* __restrict__ dst, int n4)
{
    int i = blockIdx.x * 256 + threadIdx.x;
    const int stride = gridDim.x * 256;
    for (; i < n4; i += stride) {
        const float4 v = ((const float4*)src)[i];
        bf16x4v o;
        o[0] = (bf16_t)v.x; o[1] = (bf16_t)v.y; o[2] = (bf16_t)v.z; o[3] = (bf16_t)v.w;
        ((bf16x4v*)dst)[i] = o;
    }
}

// ---------------- weight transposes (f32 (K,N) -> bf16 (N,K)) ----------------
__global__ __launch_bounds__(256) void k_cvtW(
    const float* __restrict__ linW, const float* __restrict__ WW,
    const float* __restrict__ UfW, const float* __restrict__ UiW,
    bf16_t* __restrict__ linWt, bf16_t* __restrict__ WWt,
    bf16_t* __restrict__ UfWt, bf16_t* __restrict__ UiWt)
{
    int i = blockIdx.x * 256 + threadIdx.x;      // total 786432
    if (i < 262144) {                            // linW (1024,256) -> (256,1024)
        const int rr = i >> 8, cc = i & 255;
        linWt[(size_t)cc * 1024 + rr] = (bf16_t)linW[i];
        return;
    }
    i -= 262144;
    if (i < 262144) {                            // WW (256,1024) -> (1024,256)
        const int rr = i >> 10, cc = i & 1023;
        WWt[(size_t)cc * 256 + rr] = (bf16_t)WW[i];
        return;
    }
    i -= 262144;
    if (i < 65536) {                             // UfW (256,256) -> (256,256)
        const int rr = i >> 8, cc = i & 255;
        UfWt[(size_t)cc * 256 + rr] = (bf16_t)UfW[i];
        return;
    }
    i -= 65536;
    if (i < 196608) {                            // UiW (256,768) -> (768,256)
        const int rr = i / 768, cc = i - rr * 768;
        UiWt[(size_t)cc * 256 + rr] = (bf16_t)UiW[i];
    }
}

// ---------------- zero the dummy rows (1536 B = 384 f32 each) of both state buffers ----------------
__global__ __launch_bounds__(256) void k_zero(float* __restrict__ SA, float* __restrict__ SB)
{
    const int t = threadIdx.x;
    float* a = SA + (size_t)ZROW * 384;
    float* b = SB + (size_t)ZROW * 384;
    for (int i = t; i < 384; i += 256) { a[i] = 0.f; b[i] = 0.f; }
}

// ---------------- embed GEMM (round-3 measured-best) + xsm slice write ----------------
__global__ __launch_bounds__(256) void k_embed(
    const int* __restrict__ tok1, const int* __restrict__ tok2,
    const bf16_t* __restrict__ Ebf, const bf16_t* __restrict__ linWt,
    const float* __restrict__ linb, bf16_t* __restrict__ xout,
    bf16_t* __restrict__ xsm)
{
    __shared__ int toff[64][SS];
    const int t = threadIdx.x;
    const int m0 = blockIdx.x * 64;
    {
        const int lr = t >> 2, s = t & 3;
        const int m = m0 + lr;
        const int e = (m >= LN) ? 1 : 0;
        const int rrow = m - e * LN;
        const int* tok = e ? tok2 : tok1;
        toff[lr][s] = tok[(size_t)rrow * SS + s] * HH;
    }
    __syncthreads();
    const int lane = t & 63, w = t >> 6;
    const int wm = w >> 1, wn = w & 1;
    const int r = lane & 15, kg = lane >> 4;
    const int lr0 = wm * 32 + r, lr1 = lr0 + 16;
    const bf16_t* bp[8];
    #pragma unroll
    for (int j = 0; j < 8; ++j)
        bp[j] = linWt + (size_t)(wn * 128 + j * 16 + r) * 1024 + kg * 8;

    const f32x4 zero = {0.f, 0.f, 0.f, 0.f};
    f32x4 acc[2][8];
    #pragma unroll
    for (int mi = 0; mi < 2; ++mi)
        #pragma unroll
        for (int j = 0; j < 8; ++j) acc[mi][j] = zero;

    for (int k0 = 0; k0 < 1024; k0 += 32) {
        const int s = k0 >> 8, off = (k0 & 255) + kg * 8;
        const bf16x8 a0 = *(const bf16x8*)(Ebf + (size_t)toff[lr0][s] + off);
        const bf16x8 a1 = *(const bf16x8*)(Ebf + (size_t)toff[lr1][s] + off);
        #pragma unroll
        for (int j = 0; j < 8; ++j) {
            const bf16x8 b = *(const bf16x8*)bp[j];
            acc[0][j] = __builtin_amdgcn_mfma_f32_16x16x32_bf16(a0, b, acc[0][j], 0, 0, 0);
            acc[1][j] = __builtin_amdgcn_mfma_f32_16x16x32_bf16(a1, b, acc[1][j], 0, 0, 0);
            bp[j] += 32;
        }
    }
    const int e0 = (m0 >= LN) ? 1 : 0;
    const int lblk = (m0 - e0 * LN) >> 11;           // block-uniform (2048 % 64 == 0)
    const int nbase = m0 & (NN - 1);
    const int crow = m0 + wm * 32 + kg * 4;
    const int lrow = wm * 32 + kg * 4;
    #pragma unroll
    for (int j = 0; j < 8; ++j) {
        const int ccol = wn * 128 + j * 16 + r;
        const float bv = linb[ccol];
        #pragma unroll
        for (int mi = 0; mi < 2; ++mi)
            #pragma unroll
            for (int jj = 0; jj < 4; ++jj) {
                const bf16_t val = (bf16_t)(acc[mi][j][jj] + bv);
                xout[(size_t)(crow + mi * 16 + jj) * HH + ccol] = val;
                if (lblk == LL - 1)
                    xsm[((size_t)e0 * NN + nbase + lrow + mi * 16 + jj) * HH + ccol] = val;
            }
    }
}

// ---------------- dedicated Wx GEMM with LDS-staged coalesced stores ----------------
// grid (4, 768) x 256 thr (2x2 waves); block tile 64 rows x 256 cols.
#define CTS 260   // LDS row stride (bf16) for C-tile staging
__global__ __launch_bounds__(256) void k_wx(
    const bf16_t* __restrict__ xbf, const bf16_t* __restrict__ WWt,
    const float* __restrict__ Wb, bf16_t* __restrict__ Wxs)
{
    __shared__ __align__(16) bf16_t ct[64 * CTS];   // 33,280 B
    const int n0 = blockIdx.x * 256;
    const int m0 = blockIdx.y * 64;
    const int t = threadIdx.x;
    const int lane = t & 63, w = t >> 6;
    const int wm = w >> 1, wn = w & 1;
    const int r = lane & 15, kg = lane >> 4;
    const int lr0 = wm * 32 + r, lr1 = lr0 + 16;
    const bf16_t* ap0 = xbf + (size_t)(m0 + lr0) * HH + kg * 8;
    const bf16_t* ap1 = xbf + (size_t)(m0 + lr1) * HH + kg * 8;
    const bf16_t* bp[8];
    #pragma unroll
    for (int j = 0; j < 8; ++j)
        bp[j] = WWt + (size_t)(n0 + wn * 128 + j * 16 + r) * HH + kg * 8;

    const f32x4 zero = {0.f, 0.f, 0.f, 0.f};
    f32x4 acc[2][8];
    #pragma unroll
    for (int mi = 0; mi < 2; ++mi)
        #pragma unroll
        for (int j = 0; j < 8; ++j) acc[mi][j] = zero;

    for (int k0 = 0; k0 < HH; k0 += 32) {
        const bf16x8 a0 = *(const bf16x8*)(ap0 + k0);
        const bf16x8 a1 = *(const bf16x8*)(ap1 + k0);
        #pragma unroll
        for (int j = 0; j < 8; ++j) {
            const bf16x8 b = *(const bf16x8*)bp[j];
            acc[0][j] = __builtin_amdgcn_mfma_f32_16x16x32_bf16(a0, b, acc[0][j], 0, 0, 0);
            acc[1][j] = __builtin_amdgcn_mfma_f32_16x16x32_bf16(a1, b, acc[1][j], 0, 0, 0);
            bp[j] += 32;
        }
    }
    // stage C tile into LDS (conflict-light scalar writes)
    const int lrow = wm * 32 + kg * 4;
    #pragma unroll
    for (int j = 0; j < 8; ++j) {
        const int ccol = wn * 128 + j * 16 + r;
        const float bv = Wb[n0 + ccol];
        #pragma unroll
        for (int mi = 0; mi < 2; ++mi)
            #pragma unroll
            for (int jj = 0; jj < 4; ++jj)
                ct[(lrow + mi * 16 + jj) * CTS + ccol] = (bf16_t)(acc[mi][j][jj] + bv);
    }
    __syncthreads();
    // coalesced write-out: each wave writes 2 rows x 512 B contiguous per pass
    const int slice = t & 31, rw = t >> 5;
    #pragma unroll
    for (int i = 0; i < 8; ++i) {
        const int row = i * 8 + rw;
        const bf16x8 v = *(const bf16x8*)(ct + row * CTS + slice * 8);
        *(bf16x8*)(Wxs + (size_t)(m0 + row) * 1024 + n0 + slice * 8) = v;
    }
}

// ---------------- step kernel v3: Wx precomputed; gathers issued at entry ----------------
// 256 blocks x 512 thr (8 waves), 16 rows/block.
__global__ __launch_bounds__(512, 2) void k_step2(
    const int* __restrict__ idx1, const int* __restrict__ idx2, const int l,
    const bf16_t* __restrict__ UfWt, const float* __restrict__ Ufb,
    const bf16_t* __restrict__ UiWt, const float* __restrict__ Uib,
    const bf16_t* __restrict__ Wxs,
    const char* __restrict__ Sprev, char* __restrict__ Snext)
{
    __shared__ __align__(16) bf16_t iuoL[16 * 768];   // 24 KB
    __shared__ __align__(16) bf16_t hsumL[16 * 256];  // 8 KB (hsum, later h_next; swizzled)

    const int t = threadIdx.x;
    const int bid = blockIdx.x;
    const int x  = bid & 7;
    const int e  = x >> 2;
    const int n0 = ((bid >> 3) * 4 + (x & 3)) * 16;
    const int g0 = e * NN + n0;
    const int lane = t & 63, w = t >> 6;
    const int r = lane & 15, kg = lane >> 4;
    const f32x4 zero = {0.f, 0.f, 0.f, 0.f};

    const int rr = t >> 5, sl = t & 31;
    const int ss = (sl + 4 * (rr & 7)) & 31;

    int ch[KK];
    {
        const int* idxp = (e ? idx2 : idx1) + ((size_t)l * NN + n0 + rr) * KK;
        const int4 i0 = *(const int4*)idxp;
        const int4 i1 = *(const int4*)(idxp + 4);
        ch[0] = i0.x; ch[1] = i0.y; ch[2] = i0.z; ch[3] = i0.w;
        ch[4] = i1.x; ch[5] = i1.y; ch[6] = i1.z; ch[7] = i1.w;
        #pragma unroll
        for (int k = 0; k < KK; ++k)
            ch[k] = (ch[k] >= 1) ? (e * NN + ch[k] - 1) : ZROW;
    }

    // ---- entry: issue ALL independent loads ----
    const bf16_t* wxp = Wxs + ((size_t)e * LN + (size_t)l * NN + n0 + rr) * 1024;
    const bf16x8 wfv = *(const bf16x8*)(wxp + sl * 8);
    const bf16x8 wiv = *(const bf16x8*)(wxp + 256 + sl * 8);
    const bf16x8 wuv = *(const bf16x8*)(wxp + 512 + sl * 8);
    const bf16x8 wov = *(const bf16x8*)(wxp + 768 + sl * 8);
    bf16x8 hv[KK], fv[KK], cv[KK];
    #pragma unroll
    for (int k = 0; k < KK; ++k) {
        const char* row = Sprev + (size_t)ch[k] * SROW;
        hv[k] = *(const bf16x8*)(row + sl * 16);
        fv[k] = *(const bf16x8*)(row + 512 + sl * 16);
        cv[k] = *(const bf16x8*)(row + 1024 + sl * 16);
    }

    // ---- hsum -> LDS ----
    {
        float hs[8] = {0.f, 0.f, 0.f, 0.f, 0.f, 0.f, 0.f, 0.f};
        #pragma unroll
        for (int k = 0; k < KK; ++k) {
            #pragma unroll
            for (int j = 0; j < 8; ++j) hs[j] += (float)hv[k][j];
        }
        bf16x8 o;
        #pragma unroll
        for (int j = 0; j < 8; ++j) o[j] = (bf16_t)hs[j];
        *(bf16x8*)(hsumL + rr * 256 + ss * 8) = o;
    }
    __syncthreads();   // SYNC1: hsumL visible

    // ---- iuo = hsum @ UiW + Uib ----
    {
        const bf16_t* bu[6];
        #pragma unroll
        for (int j = 0; j < 6; ++j)
            bu[j] = UiWt + (size_t)((6 * w + j) * 16 + r) * HH + kg * 8;
        f32x4 acc[6];
        #pragma unroll
        for (int j = 0; j < 6; ++j) acc[j] = zero;
        for (int k0 = 0; k0 < HH; k0 += 32) {
            const int sa = (((k0 >> 3) + kg) + 4 * (r & 7)) & 31;
            const bf16x8 a = *(const bf16x8*)(hsumL + r * 256 + sa * 8);
            #pragma unroll
            for (int j = 0; j < 6; ++j) {
                const bf16x8 b = *(const bf16x8*)bu[j];
                acc[j] = __builtin_amdgcn_mfma_f32_16x16x32_bf16(a, b, acc[j], 0, 0, 0);
                bu[j] += 32;
            }
        }
        #pragma unroll
        for (int j = 0; j < 6; ++j) {
            const int col = (6 * w + j) * 16 + r;
            const float bv = Uib[col];
            #pragma unroll
            for (int jj = 0; jj < 4; ++jj)
                iuoL[(size_t)(kg * 4 + jj) * 768 + col] = (bf16_t)(acc[j][jj] + bv);
        }
    }

    // ---- ba from c/Hf/Wf (registers) ----
    float ba[8] = {0.f, 0.f, 0.f, 0.f, 0.f, 0.f, 0.f, 0.f};
    {
        float wf[8];
        #pragma unroll
        for (int j = 0; j < 8; ++j) wf[j] = (float)wfv[j];
        #pragma unroll
        for (int k = 0; k < KK; ++k) {
            #pragma unroll
            for (int j = 0; j < 8; ++j) {
                const float fk = sigmoidf_(wf[j] + (float)fv[k][j]);
                ba[j] = fmaf(fk, (float)cv[k][j], ba[j]);
            }
        }
    }
    __syncthreads();   // SYNC2: iuoL visible; hsum reads done

    // ---- gates ----
    {
        const bf16x8 iv = *(const bf16x8*)(iuoL + (size_t)rr * 768 + sl * 8);
        const bf16x8 uv = *(const bf16x8*)(iuoL + (size_t)rr * 768 + 256 + sl * 8);
        const bf16x8 ov = *(const bf16x8*)(iuoL + (size_t)rr * 768 + 512 + sl * 8);
        bf16x8 ncb, nhb;
        #pragma unroll
        for (int j = 0; j < 8; ++j) {
            const float ig = sigmoidf_((float)iv[j] + (float)wiv[j]);
            const float ug = tanhf((float)uv[j] + (float)wuv[j]);
            const float og = sigmoidf_((float)ov[j] + (float)wov[j]);
            const float nc = fmaf(ig, ug, ba[j]);
            ncb[j] = (bf16_t)nc;
            nhb[j] = (bf16_t)(og * tanhf(nc));
        }
        char* rowN = Snext + (size_t)(g0 + rr) * SROW;
        *(bf16x8*)(rowN + sl * 16) = nhb;
        *(bf16x8*)(rowN + 1024 + sl * 16) = ncb;
        *(bf16x8*)(hsumL + rr * 256 + ss * 8) = nhb;
    }

    if (l < LL - 1) {
        __syncthreads();   // SYNC3: h_next visible
        const int ct0 = 2 * w;
        const bf16_t* bq0 = UfWt + (size_t)(ct0 * 16 + r) * HH + kg * 8;
        const bf16_t* bq1 = bq0 + (size_t)16 * HH;
        f32x4 ac0 = zero, ac1 = zero;
        for (int k0 = 0; k0 < HH; k0 += 32) {
            const int sa = (((k0 >> 3) + kg) + 4 * (r & 7)) & 31;
            const bf16x8 a = *(const bf16x8*)(hsumL + r * 256 + sa * 8);
            const bf16x8 b0 = *(const bf16x8*)bq0;
            const bf16x8 b1 = *(const bf16x8*)bq1;
            ac0 = __builtin_amdgcn_mfma_f32_16x16x32_bf16(a, b0, ac0, 0, 0, 0);
            ac1 = __builtin_amdgcn_mfma_f32_16x16x32_bf16(a, b1, ac1, 0, 0, 0);
            bq0 += 32; bq1 += 32;
        }
        const int c0 = ct0 * 16 + r, c1 = c0 + 16;
        const float bv0 = Ufb[c0], bv1 = Ufb[c1];
        #pragma unroll
        for (int jj = 0; jj < 4; ++jj) {
            bf16_t* fr = (bf16_t*)(Snext + (size_t)(g0 + kg * 4 + jj) * SROW + 512);
            fr[c0] = (bf16_t)(ac0[jj] + bv0);
            fr[c1] = (bf16_t)(ac1[jj] + bv1);
        }
    }
}

// ---------------- siamese head (x from xsm slice) ----------------
__global__ __launch_bounds__(256) void k_final2(
    const char* __restrict__ Sfin, const bf16_t* __restrict__ xsm,
    const float* __restrict__ dW, const float* __restrict__ db,
    const float* __restrict__ oW, const float* __restrict__ ob,
    float* __restrict__ out)
{
    __shared__ __align__(16) float ad[8][HH];
    __shared__ __align__(16) float xx[8][512];
    const int t = threadIdx.x;
    const int n0 = blockIdx.x * 8;
    #pragma unroll
    for (int rr = 0; rr < 8; ++rr) {
        const int n = n0 + rr;
        const float h1 = (float)((const bf16_t*)(Sfin + (size_t)n * SROW))[t]
                       + (float)xsm[(size_t)n * HH + t];
        const float h2 = (float)((const bf16_t*)(Sfin + (size_t)(NN + n) * SROW))[t]
                       + (float)xsm[((size_t)NN + n) * HH + t];
        ad[rr][t] = fabsf(h1 - h2);
    }
    __syncthreads();
    float a0[8], a1[8];
    #pragma unroll
    for (int rr = 0; rr < 8; ++rr) { a0[rr] = 0.f; a1[rr] = 0.f; }
    for (int k = 0; k < HH; k += 4) {
        #pragma unroll
        for (int kk = 0; kk < 4; ++kk) {
            const float b0 = dW[(size_t)(k + kk) * 512 + t];
            const float b1 = dW[(size_t)(k + kk) * 512 + 256 + t];
            #pragma unroll
            for (int rr = 0; rr < 8; ++rr) {
                const float av = ad[rr][k + kk];
                a0[rr] = fmaf(av, b0, a0[rr]);
                a1[rr] = fmaf(av, b1, a1[rr]);
            }
        }
    }
    const float db0 = db[t], db1 = db[256 + t];
    #pragma unroll
    for (int rr = 0; rr < 8; ++rr) {
        xx[rr][t] = tanhf(a0[rr] + db0);
        xx[rr][256 + t] = tanhf(a1[rr] + db1);
    }
    __syncthreads();
    const int w = t >> 6, lane = t & 63;
    for (int rr = w; rr < 8; rr += 4) {
        float p0 = 0.f, p1 = 0.f;
        for (int k = lane; k < 512; k += 64) {
            const float xv = xx[rr][k];
            p0 = fmaf(xv, oW[2 * k + 0], p0);
            p1 = fmaf(xv, oW[2 * k + 1], p1);
        }
        #pragma unroll
        for (int off = 32; off > 0; off >>= 1) {
            p0 += __shfl_down(p0, off);
            p1 += __shfl_down(p1, off);
        }
        if (lane == 0) {
            const float l0 = p0 + ob[0], l1 = p1 + ob[1];
            const float mx = fmaxf(l0, l1);
            const float e0 = expf(l0 - mx), e1 = expf(l1 - mx);
            const float inv = 1.f / (e0 + e1);
            out[(size_t)(n0 + rr) * 2 + 0] = e0 * inv;
            out[(size_t)(n0 + rr) * 2 + 1] = e1 * inv;
        }
    }
}

// ================= fallback (round-14) kernels =================
__global__ __launch_bounds__(512, 2) void k_step(
    const bf16_t* __restrict__ xbf,
    const int* __restrict__ idx1, const int* __restrict__ idx2, const int l,
    const bf16_t* __restrict__ UfWt, const float* __restrict__ Ufb,
    const bf16_t* __restrict__ UiWt, const float* __restrict__ Uib,
    const bf16_t* __restrict__ WWt, const float* __restrict__ Wb,
    const char* __restrict__ Sprev, char* __restrict__ Snext)
{
    __shared__ __align__(16) bf16_t WxL[16 * 1024];
    __shared__ __align__(16) bf16_t iuoL[16 * 768];
    __shared__ __align__(16) bf16_t hsumL[16 * 256];
    const int t = threadIdx.x;
    const int bid = blockIdx.x;
    const int x  = bid & 7;
    const int e  = x >> 2;
    const int n0 = ((bid >> 3) * 4 + (x & 3)) * 16;
    const int g0 = e * NN + n0;
    const int lane = t & 63, w = t >> 6;
    const int r = lane & 15, kg = lane >> 4;
    const f32x4 zero = {0.f, 0.f, 0.f, 0.f};
    const int rr = t >> 5, sl = t & 31;
    const int ss = (sl + 4 * (rr & 7)) & 31;
    int ch[KK];
    {
        const int* idxp = (e ? idx2 : idx1) + ((size_t)l * NN + n0 + rr) * KK;
        const int4 i0 = *(const int4*)idxp;
        const int4 i1 = *(const int4*)(idxp + 4);
        ch[0] = i0.x; ch[1] = i0.y; ch[2] = i0.z; ch[3] = i0.w;
        ch[4] = i1.x; ch[5] = i1.y; ch[6] = i1.z; ch[7] = i1.w;
        #pragma unroll
        for (int k = 0; k < KK; ++k)
            ch[k] = (ch[k] >= 1) ? (e * NN + ch[k] - 1) : ZROW;
    }
    bf16x8 hv[KK];
    #pragma unroll
    for (int k = 0; k < KK; ++k)
        hv[k] = *(const bf16x8*)(Sprev + (size_t)ch[k] * SROW + sl * 16);
    const bf16_t* xrow = xbf + ((size_t)e * LN + (size_t)l * NN + n0 + r) * HH + kg * 8;
    bf16x8 aWx[8];
    #pragma unroll
    for (int k = 0; k < 8; ++k) aWx[k] = *(const bf16x8*)(xrow + k * 32);
    {
        const bf16_t* bw[8];
        #pragma unroll
        for (int j = 0; j < 8; ++j)
            bw[j] = WWt + (size_t)((8 * w + j) * 16 + r) * HH + kg * 8;
        f32x4 acc[8];
        #pragma unroll
        for (int j = 0; j < 8; ++j) acc[j] = zero;
        #pragma unroll
        for (int k = 0; k < 8; ++k) {
            #pragma unroll
            for (int j = 0; j < 8; ++j) {
                const bf16x8 b = *(const bf16x8*)bw[j];
                acc[j] = __builtin_amdgcn_mfma_f32_16x16x32_bf16(aWx[k], b, acc[j], 0, 0, 0);
                bw[j] += 32;
            }
        }
        #pragma unroll
        for (int j = 0; j < 8; ++j) {
            const int col = (8 * w + j) * 16 + r;
            const float bv = Wb[col];
            #pragma unroll
            for (int jj = 0; jj < 4; ++jj)
                WxL[(size_t)(kg * 4 + jj) * 1024 + col] = (bf16_t)(acc[j][jj] + bv);
        }
    }
    {
        float hs[8] = {0.f, 0.f, 0.f, 0.f, 0.f, 0.f, 0.f, 0.f};
        #pragma unroll
        for (int k = 0; k < KK; ++k) {
            #pragma unroll
            for (int j = 0; j < 8; ++j) hs[j] += (float)hv[k][j];
        }
        bf16x8 o;
        #pragma unroll
        for (int j = 0; j < 8; ++j) o[j] = (bf16_t)hs[j];
        *(bf16x8*)(hsumL + rr * 256 + ss * 8) = o;
    }
    __syncthreads();
    bf16x8 cv[KK], fvv[KK];
    #pragma unroll
    for (int k = 0; k < KK; ++k) {
        const char* row = Sprev + (size_t)ch[k] * SROW;
        fvv[k] = *(const bf16x8*)(row + 512 + sl * 16);
        cv[k]  = *(const bf16x8*)(row + 1024 + sl * 16);
    }
    {
        const bf16_t* bu[6];
        #pragma unroll
        for (int j = 0; j < 6; ++j)
            bu[j] = UiWt + (size_t)((6 * w + j) * 16 + r) * HH + kg * 8;
        f32x4 acc[6];
        #pragma unroll
        for (int j = 0; j < 6; ++j) acc[j] = zero;
        for (int k0 = 0; k0 < HH; k0 += 32) {
            const int sa = (((k0 >> 3) + kg) + 4 * (r & 7)) & 31;
            const bf16x8 a = *(const bf16x8*)(hsumL + r * 256 + sa * 8);
            #pragma unroll
            for (int j = 0; j < 6; ++j) {
                const bf16x8 b = *(const bf16x8*)bu[j];
                acc[j] = __builtin_amdgcn_mfma_f32_16x16x32_bf16(a, b, acc[j], 0, 0, 0);
                bu[j] += 32;
            }
        }
        #pragma unroll
        for (int j = 0; j < 6; ++j) {
            const int col = (6 * w + j) * 16 + r;
            const float bv = Uib[col];
            #pragma unroll
            for (int jj = 0; jj < 4; ++jj)
                iuoL[(size_t)(kg * 4 + jj) * 768 + col] = (bf16_t)(acc[j][jj] + bv);
        }
    }
    float ba[8] = {0.f, 0.f, 0.f, 0.f, 0.f, 0.f, 0.f, 0.f};
    {
        float wf[8];
        const bf16x8 wv = *(const bf16x8*)(WxL + (size_t)rr * 1024 + sl * 8);
        #pragma unroll
        for (int j = 0; j < 8; ++j) wf[j] = (float)wv[j];
        #pragma unroll
        for (int k = 0; k < KK; ++k) {
            #pragma unroll
            for (int j = 0; j < 8; ++j) {
                const float fk = sigmoidf_(wf[j] + (float)fvv[k][j]);
                ba[j] = fmaf(fk, (float)cv[k][j], ba[j]);
            }
        }
    }
    __syncthreads();
    {
        const bf16x8 wiv = *(const bf16x8*)(WxL + (size_t)rr * 1024 + 256 + sl * 8);
        const bf16x8 wuv = *(const bf16x8*)(WxL + (size_t)rr * 1024 + 512 + sl * 8);
        const bf16x8 wov = *(const bf16x8*)(WxL + (size_t)rr * 1024 + 768 + sl * 8);
        const bf16x8 iv  = *(const bf16x8*)(iuoL + (size_t)rr * 768 + sl * 8);
        const bf16x8 uv  = *(const bf16x8*)(iuoL + (size_t)rr * 768 + 256 + sl * 8);
        const bf16x8 ov  = *(const bf16x8*)(iuoL + (size_t)rr * 768 + 512 + sl * 8);
        bf16x8 ncb, nhb;
        #pragma unroll
        for (int j = 0; j < 8; ++j) {
            const float ig = sigmoidf_((float)iv[j] + (float)wiv[j]);
            const float ug = tanhf((float)uv[j] + (float)wuv[j]);
            const float og = sigmoidf_((float)ov[j] + (float)wov[j]);
            const float nc = fmaf(ig, ug, ba[j]);
            ncb[j] = (bf16_t)nc;
            nhb[j] = (bf16_t)(og * tanhf(nc));
        }
        char* rowN = Snext + (size_t)(g0 + rr) * SROW;
        *(bf16x8*)(rowN + sl * 16) = nhb;
        *(bf16x8*)(rowN + 1024 + sl * 16) = ncb;
        *(bf16x8*)(hsumL + rr * 256 + ss * 8) = nhb;
    }
    if (l < LL - 1) {
        __syncthreads();
        const int ct0 = 2 * w;
        const bf16_t* bq0 = UfWt + (size_t)(ct0 * 16 + r) * HH + kg * 8;
        const bf16_t* bq1 = bq0 + (size_t)16 * HH;
        f32x4 ac0 = zero, ac1 = zero;
        for (int k0 = 0; k0 < HH; k0 += 32) {
            const int sa = (((k0 >> 3) + kg) + 4 * (r & 7)) & 31;
            const bf16x8 a = *(const bf16x8*)(hsumL + r * 256 + sa * 8);
            const bf16x8 b0 = *(const bf16x8*)bq0;
            const bf16x8 b1 = *(const bf16x8*)bq1;
            ac0 = __builtin_amdgcn_mfma_f32_16x16x32_bf16(a, b0, ac0, 0, 0, 0);
            ac1 = __builtin_amdgcn_mfma_f32_16x16x32_bf16(a, b1, ac1, 0, 0, 0);
            bq0 += 32; bq1 += 32;
        }
        const int c0 = ct0 * 16 + r, c1 = c0 + 16;
        const float bv0 = Ufb[c0], bv1 = Ufb[c1];
        #pragma unroll
        for (int jj = 0; jj < 4; ++jj) {
            bf16_t* fr = (bf16_t*)(Snext + (size_t)(g0 + kg * 4 + jj) * SROW + 512);
            fr[c0] = (bf16_t)(ac0[jj] + bv0);
            fr[c1] = (bf16_t)(ac1[jj] + bv1);
        }
    }
}

__global__ __launch_bounds__(256) void k_final(
    const char* __restrict__ Sfin, const bf16_t* __restrict__ xbf,
    const float* __restrict__ dW, const float* __restrict__ db,
    const float* __restrict__ oW, const float* __restrict__ ob,
    float* __restrict__ out)
{
    __shared__ __align__(16) float ad[8][HH];
    __shared__ __align__(16) float xx[8][512];
    const int t = threadIdx.x;
    const int n0 = blockIdx.x * 8;
    const size_t xoff1 = (size_t)(LL - 1) * NN * HH;
    const size_t xoff2 = (size_t)LN * HH + xoff1;
    #pragma unroll
    for (int rr = 0; rr < 8; ++rr) {
        const int n = n0 + rr;
        const float h1 = (float)((const bf16_t*)(Sfin + (size_t)n * SROW))[t]
                       + (float)xbf[xoff1 + (size_t)n * HH + t];
        const float h2 = (float)((const bf16_t*)(Sfin + (size_t)(NN + n) * SROW))[t]
                       + (float)xbf[xoff2 + (size_t)n * HH + t];
        ad[rr][t] = fabsf(h1 - h2);
    }
    __syncthreads();
    float a0[8], a1[8];
    #pragma unroll
    for (int rr = 0; rr < 8; ++rr) { a0[rr] = 0.f; a1[rr] = 0.f; }
    for (int k = 0; k < HH; k += 4) {
        #pragma unroll
        for (int kk = 0; kk < 4; ++kk) {
            const float b0 = dW[(size_t)(k + kk) * 512 + t];
            const float b1 = dW[(size_t)(k + kk) * 512 + 256 + t];
            #pragma unroll
            for (int rr = 0; rr < 8; ++rr) {
                const float av = ad[rr][k + kk];
                a0[rr] = fmaf(av, b0, a0[rr]);
                a1[rr] = fmaf(av, b1, a1[rr]);
            }
        }
    }
    const float db0 = db[t], db1 = db[256 + t];
    #pragma unroll
    for (int rr = 0; rr < 8; ++rr) {
        xx[rr][t] = tanhf(a0[rr] + db0);
        xx[rr][256 + t] = tanhf(a1[rr] + db1);
    }
    __syncthreads();
    const int w = t >> 6, lane = t & 63;
    for (int rr = w; rr < 8; rr += 4) {
        float p0 = 0.f, p1 = 0.f;
        for (int k = lane; k < 512; k += 64) {
            const float xv = xx[rr][k];
            p0 = fmaf(xv, oW[2 * k + 0], p0);
            p1 = fmaf(xv, oW[2 * k + 1], p1);
        }
        #pragma unroll
        for (int off = 32; off > 0; off >>= 1) {
            p0 += __shfl_down(p0, off);
            p1 += __shfl_down(p1, off);
        }
        if (lane == 0) {
            const float l0 = p0 + ob[0], l1 = p1 + ob[1];
            const float mx = fmaxf(l0, l1);
            const float e0 = expf(l0 - mx), e1 = expf(l1 - mx);
            const float inv = 1.f / (e0 + e1);
            out[(size_t)(n0 + rr) * 2 + 0] = e0 * inv;
            out[(size_t)(n0 + rr) * 2 + 1] = e1 * inv;
        }
    }
}

extern "C" void kernel_launch(void* const* d_in, const int* in_sizes, int n_in,
                              void* d_out, int out_size, void* d_ws, size_t ws_size,
                              hipStream_t stream) {
    (void)in_sizes; (void)n_in; (void)out_size;
    const int*   tok1 = (const int*)d_in[0];
    const int*   idx1 = (const int*)d_in[1];
    const int*   tok2 = (const int*)d_in[2];
    const int*   idx2 = (const int*)d_in[3];
    const float* E    = (const float*)d_in[4];
    const float* linW = (const float*)d_in[5];
    const float* linb = (const float*)d_in[6];
    const float* UfW  = (const float*)d_in[7];
    const float* Ufb  = (const float*)d_in[8];
    const float* UiW  = (const float*)d_in[9];
    const float* Uib  = (const float*)d_in[10];
    const float* WW   = (const float*)d_in[11];
    const float* Wb   = (const float*)d_in[12];
    const float* dW   = (const float*)d_in[13];
    const float* db   = (const float*)d_in[14];
    const float* oW   = (const float*)d_in[15];
    const float* ob   = (const float*)d_in[16];
    float* out = (float*)d_out;

    // main-path ws: xbf(25,165,824; SA/SB alias after k_wx) | Wxs(100,663,296; Ebf aliases)
    //               | xsm(2,097,152) | weights(1,572,864)  = 129,499,136 B
    const size_t NEED = 129499136ull;

    if (ws_size >= NEED) {
        bf16_t* xbf = (bf16_t*)d_ws;                        // 25,165,824 B
        char*   SA  = (char*)d_ws;                          // aliases xbf (dead after k_wx)
        char*   SB  = (char*)d_ws + 6292992;
        char*   r2  = (char*)d_ws + 25165824;
        bf16_t* Wxs = (bf16_t*)r2;                          // 100,663,296 B
        bf16_t* Ebf = (bf16_t*)r2;                          // aliases Wxs (dead after embed)
        bf16_t* xsm = (bf16_t*)(r2 + 100663296);            // 2,097,152 B
        bf16_t* linWt = (bf16_t*)(r2 + 100663296 + 2097152);
        bf16_t* WWt   = linWt + (size_t)262144;
        bf16_t* UfWt  = WWt   + (size_t)262144;
        bf16_t* UiWt  = UfWt  + (size_t)65536;

        k_cvtE<<<2048, 256, 0, stream>>>(E, Ebf, VV * HH / 4);
        k_cvtW<<<3072, 256, 0, stream>>>(linW, WW, UfW, UiW, linWt, WWt, UfWt, UiWt);
        k_embed<<<768, 256, 0, stream>>>(tok1, tok2, Ebf, linWt, linb, xbf, xsm);
        k_wx<<<dim3(4, 768), 256, 0, stream>>>(xbf, WWt, Wb, Wxs);   // xbf dead after this
        k_zero<<<1, 256, 0, stream>>>((float*)SA, (float*)SB);

        char *Sp = SA, *Sn = SB;
        for (int l = 0; l < LL; ++l) {
            k_step2<<<256, 512, 0, stream>>>(idx1, idx2, l, UfWt, Ufb, UiWt, Uib,
                                             Wxs, Sp, Sn);
            char* ts = Sp; Sp = Sn; Sn = ts;
        }
        k_final2<<<NN / 8, 256, 0, stream>>>(Sp, xsm, dW, db, oW, ob, out);
    } else {
        // fallback = round-14 path
        bf16_t* xbf = (bf16_t*)d_ws;                        // 25,165,824 B
        char*   uni = (char*)(xbf + (size_t)12582912);
        bf16_t* Ebf = (bf16_t*)uni;
        char*   SA  = uni;
        char*   SB  = uni + 6292992;
        bf16_t* linWt = (bf16_t*)(uni + 25600000);
        bf16_t* WWt   = linWt + (size_t)262144;
        bf16_t* UfWt  = WWt   + (size_t)262144;
        bf16_t* UiWt  = UfWt  + (size_t)65536;

        k_cvtE<<<2048, 256, 0, stream>>>(E, Ebf, VV * HH / 4);
        k_cvtW<<<3072, 256, 0, stream>>>(linW, WW, UfW, UiW, linWt, WWt, UfWt, UiWt);
        k_embed<<<768, 256, 0, stream>>>(tok1, tok2, Ebf, linWt, linb, xbf,
                                         xbf + (size_t)(LL - 1) * NN * HH);
        k_zero<<<1, 256, 0, stream>>>((float*)SA, (float*)SB);

        char *Sp = SA, *Sn = SB;
        for (int l = 0; l < LL; ++l) {
            k_step<<<256, 512, 0, stream>>>(xbf, idx1, idx2, l,
                                            UfWt, Ufb, UiWt, Uib, WWt, Wb, Sp, Sn);
            char* ts = Sp; Sp = Sn; Sn = ts;
        }
        k_final<<<NN / 8, 256, 0, stream>>>(Sp, xbf, dW, db, oW, ob, out);
    }
}